// Round 2
// baseline (1359.182 us; speedup 1.0000x reference)
//
#include <hip/hip_runtime.h>

#define N_NODES 100000
#define N_EDGES 3200000
#define C_IN 256
#define C_H 64
#define C_OUT 128
#define NBLK_N 391   // ceil(N_NODES/256)
#define G2 1024      // blocks for fused gather2+pool

typedef unsigned int u32;
typedef unsigned short u16;
typedef unsigned long long u64;

// ---------- bf16 helpers (bf16 = upper 16 bits of fp32) ----------
__device__ __forceinline__ float bflo(u32 p) {
    union { u32 i; float f; } v; v.i = p << 16; return v.f;
}
__device__ __forceinline__ float bfhi(u32 p) {
    union { u32 i; float f; } v; v.i = p & 0xffff0000u; return v.f;
}
__device__ __forceinline__ float bf2f(u16 u) {
    union { u32 i; float f; } v; v.i = ((u32)u) << 16; return v.f;
}
__device__ __forceinline__ u16 f2bf(float f) {
    union { float f; u32 i; } v; v.f = f;
    u32 x = v.i;
    return (u16)((x + 0x7fffu + ((x >> 16) & 1u)) >> 16);  // RNE
}

// ---------- detection + canonicalization ----------
// flags[0] = 1 if float tensors are bf16, 0 if fp32
// flags[1] = 1 if edge_index is int64, 0 if int32
__global__ void k_detect(const void* __restrict__ x, const void* __restrict__ ei,
                         const void* __restrict__ W1, const void* __restrict__ b1,
                         const void* __restrict__ W2, const void* __restrict__ b2,
                         const void* __restrict__ fcW, const void* __restrict__ fcb,
                         int* __restrict__ flags,
                         u16* __restrict__ W1c, u16* __restrict__ W2c,
                         float* __restrict__ b1c, float* __restrict__ b2c,
                         float* __restrict__ fcWc, float* __restrict__ fcbc) {
    __shared__ int sf[2];
    int t = threadIdx.x;
    if (t < 64) {
        // probe x: low 16 bits of each dword. bf16 -> exponent near 127; fp32 -> uniform mantissa bits
        u32 w = ((const u32*)x)[t];
        u32 low = w & 0xffffu;
        int e = (int)((low >> 7) & 0xff);
        bool inw = (e > 96 && e < 160) || (low == 0);
        u64 m = __ballot(inw);
        if (t == 0) sf[0] = (__popcll(m) >= 60) ? 1 : 0;
    } else if (t < 128) {
        int i = t - 64;
        u32 w = ((const u32*)ei)[2 * i + 1];   // high dwords if int64
        u64 m = __ballot(w == 0);
        if (i == 0) sf[1] = (m == ~0ull) ? 1 : 0;
    }
    __syncthreads();
    if (t == 0) { flags[0] = sf[0]; flags[1] = sf[1]; }
    int isbf = sf[0];
    if (isbf) {
        const u16* w1 = (const u16*)W1;
        const u16* w2 = (const u16*)W2;
        for (int i = t; i < C_IN * C_H; i += 256) W1c[i] = w1[i];
        for (int i = t; i < C_H * C_OUT; i += 256) W2c[i] = w2[i];
        const u16* p1 = (const u16*)b1;  const u16* p2 = (const u16*)b2;
        const u16* pw = (const u16*)fcW; const u16* pb = (const u16*)fcb;
        for (int i = t; i < C_H; i += 256) b1c[i] = bf2f(p1[i]);
        for (int i = t; i < C_OUT; i += 256) b2c[i] = bf2f(p2[i]);
        for (int i = t; i < 2 * C_OUT; i += 256) fcWc[i] = bf2f(pw[i]);
        for (int i = t; i < 2; i += 256) fcbc[i] = bf2f(pb[i]);
    } else {
        const float* w1 = (const float*)W1;
        const float* w2 = (const float*)W2;
        for (int i = t; i < C_IN * C_H; i += 256) W1c[i] = f2bf(w1[i]);
        for (int i = t; i < C_H * C_OUT; i += 256) W2c[i] = f2bf(w2[i]);
        const float* p1 = (const float*)b1;  const float* p2 = (const float*)b2;
        const float* pw = (const float*)fcW; const float* pb = (const float*)fcb;
        for (int i = t; i < C_H; i += 256) b1c[i] = p1[i];
        for (int i = t; i < C_OUT; i += 256) b2c[i] = p2[i];
        for (int i = t; i < 2 * C_OUT; i += 256) fcWc[i] = pw[i];
        for (int i = t; i < 2; i += 256) fcbc[i] = pb[i];
    }
}

// ---------- CSR build ----------
__global__ void k_init(int* __restrict__ cnt) {
    int i = blockIdx.x * 256 + threadIdx.x;
    if (i < N_NODES) cnt[i] = 0;
}

__global__ void k_count(const int* __restrict__ ei, int* __restrict__ cnt,
                        const int* __restrict__ flags) {
    int is64 = flags[1];
    int e = blockIdx.x * 256 + threadIdx.x;
    if (e < N_EDGES) {
        int d = is64 ? ei[2 * (N_EDGES + e)] : ei[N_EDGES + e];
        atomicAdd(&cnt[d], 1);
    }
}

// per-block exclusive scan of cnt -> rowptr (chunk-local) + block sums
__global__ void k_scan1(const int* __restrict__ cnt, int* __restrict__ rowptr,
                        int* __restrict__ bsum) {
    __shared__ int sm[256];
    int t = threadIdx.x;
    int i = blockIdx.x * 256 + t;
    int v = (i < N_NODES) ? cnt[i] : 0;
    sm[t] = v;
    __syncthreads();
    for (int off = 1; off < 256; off <<= 1) {
        int add = (t >= off) ? sm[t - off] : 0;
        __syncthreads();
        sm[t] += add;
        __syncthreads();
    }
    if (i < N_NODES) rowptr[i] = sm[t] - v;      // exclusive
    if (t == 255) bsum[blockIdx.x] = sm[255];    // inclusive total
}

// single-block scan of the NBLK_N block sums (exclusive, in place)
__global__ void k_scan2(int* __restrict__ bsum) {
    __shared__ int sm[512];
    int t = threadIdx.x;
    int v = (t < NBLK_N) ? bsum[t] : 0;
    sm[t] = v;
    __syncthreads();
    for (int off = 1; off < 512; off <<= 1) {
        int add = (t >= off) ? sm[t - off] : 0;
        __syncthreads();
        sm[t] += add;
        __syncthreads();
    }
    if (t < NBLK_N) bsum[t] = sm[t] - v;
}

// add block offsets; init cursor; dinv = rsqrt(deg) (deg = indeg + 1, in place over cnt)
__global__ void k_finalize(int* __restrict__ rowptr, int* __restrict__ cursor,
                           int* cnt, float* dinv, const int* __restrict__ bsum) {
    int i = blockIdx.x * 256 + threadIdx.x;
    if (i < N_NODES) {
        int rp = rowptr[i] + bsum[blockIdx.x];
        rowptr[i] = rp;
        cursor[i] = rp;
        int deg = cnt[i] + 1;          // cnt/dinv alias: read before write (same thread)
        dinv[i] = rsqrtf((float)deg);
    }
    if (i == 0) rowptr[N_NODES] = N_EDGES;
}

__global__ void k_scatter(const int* __restrict__ ei, int* __restrict__ cursor,
                          int* __restrict__ csr_src, const int* __restrict__ flags) {
    int is64 = flags[1];
    int e = blockIdx.x * 256 + threadIdx.x;
    if (e < N_EDGES) {
        int s = is64 ? ei[2 * e] : ei[e];
        int d = is64 ? ei[2 * (N_EDGES + e)] : ei[N_EDGES + e];
        int p = atomicAdd(&cursor[d], 1);
        csr_src[p] = s;
    }
}

// ---------- GEMM1: h1[N,64] = x[N,256] @ W1[256,64] (fp32 acc, bf16 out) ----------
__global__ __launch_bounds__(256) void k_gemm1(const void* __restrict__ xv,
                                               const u16* __restrict__ W1c,
                                               u16* __restrict__ h1,
                                               const int* __restrict__ flags) {
    __shared__ u32 wlds[C_IN * C_H / 2];   // [256][32 pairs] packed bf16x2, 32KB
    __shared__ float xlds[16 * 257];       // 16 nodes x 256 (stride 257)
    int t = threadIdx.x;
    int nb = blockIdx.x * 16;
    int isbf = flags[0];

    const u32* w32 = (const u32*)W1c;      // 8192 dwords
#pragma unroll
    for (int it = 0; it < 32; ++it) wlds[t + it * 256] = w32[t + it * 256];

    if (isbf) {
        const u32* x32 = (const u32*)xv + (size_t)nb * (C_IN / 2);
#pragma unroll
        for (int it = 0; it < 8; ++it) {
            int d = t + it * 256;
            u32 pk = x32[d];
            int e0 = d * 2;
            int r = e0 >> 8, c = e0 & 255;
            float* dst = &xlds[r * 257 + c];
            dst[0] = bflo(pk);
            dst[1] = bfhi(pk);
        }
    } else {
        const float* xf = (const float*)xv + (size_t)nb * C_IN;
#pragma unroll
        for (int it = 0; it < 16; ++it) {
            int e = t + it * 256;
            int r = e >> 8, c = e & 255;
            xlds[r * 257 + c] = xf[e];
        }
    }
    __syncthreads();

    int jt = t & 15, nl = t >> 4;             // 16 ch-groups x 16 nodes
    const float* xr = &xlds[nl * 257];
    float a0 = 0.f, a1 = 0.f, a2 = 0.f, a3 = 0.f;
#pragma unroll 4
    for (int k = 0; k < C_IN; ++k) {
        float xvv = xr[k];
        uint2 wp = *(const uint2*)&wlds[k * 32 + jt * 2];
        a0 = fmaf(xvv, bflo(wp.x), a0);
        a1 = fmaf(xvv, bfhi(wp.x), a1);
        a2 = fmaf(xvv, bflo(wp.y), a2);
        a3 = fmaf(xvv, bfhi(wp.y), a3);
    }
    int n = nb + nl;
    u32 p0 = (u32)f2bf(a0) | ((u32)f2bf(a1) << 16);
    u32 p1 = (u32)f2bf(a2) | ((u32)f2bf(a3) << 16);
    *(uint2*)(h1 + n * C_H + jt * 4) = make_uint2(p0, p1);
}

// ---------- gather1: a1 = relu(D^-1/2 A D^-1/2 h1 + b1), one wave per node ----------
__global__ __launch_bounds__(256) void k_gather1(const int* __restrict__ rowptr,
                                                 const int* __restrict__ csr_src,
                                                 const float* __restrict__ dinv,
                                                 const u16* __restrict__ h1,
                                                 const float* __restrict__ b1c,
                                                 u16* __restrict__ a1) {
    int w = threadIdx.x >> 6, lane = threadIdx.x & 63;
    int n = blockIdx.x * 4 + w;
    if (n >= N_NODES) return;
    int beg = rowptr[n], end = rowptr[n + 1];
    float s = 0.f;
    for (int e = beg; e < end; ++e) {
        int src = csr_src[e];
        float c = dinv[src];
        s = fmaf(c, bf2f(h1[src * C_H + lane]), s);
    }
    float dn = dinv[n];
    float out = dn * s + dn * dn * bf2f(h1[n * C_H + lane]) + b1c[lane];
    a1[n * C_H + lane] = f2bf(fmaxf(out, 0.f));
}

// ---------- GEMM2: h2[N,128] = a1[N,64] @ W2[64,128] ----------
__global__ __launch_bounds__(256) void k_gemm2(const u16* __restrict__ a1,
                                               const u16* __restrict__ W2c,
                                               u16* __restrict__ h2) {
    __shared__ float wlds[C_H * C_OUT];   // 8192 floats, 32KB
    __shared__ float alds[16 * 65];       // 16 nodes x 64 (stride 65)
    int t = threadIdx.x;
    int nb = blockIdx.x * 16;

    const u32* w32 = (const u32*)W2c;     // 4096 dwords
#pragma unroll
    for (int it = 0; it < 16; ++it) {
        int d = t + it * 256;
        u32 pk = w32[d];
        int e0 = d * 2;
        wlds[e0] = bflo(pk);
        wlds[e0 + 1] = bfhi(pk);
    }
    {
        const u32* a32 = (const u32*)(a1 + (size_t)nb * C_H);  // 512 dwords
        int d = t * 2;
        uint2 pk = *(const uint2*)&a32[d];
        int e0 = d * 2;
        int r = e0 >> 6, c = e0 & 63;
        float* dst = &alds[r * 65 + c];
        dst[0] = bflo(pk.x);
        dst[1] = bfhi(pk.x);
        dst[2] = bflo(pk.y);
        dst[3] = bfhi(pk.y);
    }
    __syncthreads();

    int jt = t & 31, g = t >> 5;   // 32 ch-groups x 8 node-groups (nodes g, g+8)
    float acc[2][4] = {{0.f, 0.f, 0.f, 0.f}, {0.f, 0.f, 0.f, 0.f}};
#pragma unroll 4
    for (int k = 0; k < C_H; ++k) {
        float4 wv = *(const float4*)&wlds[k * C_OUT + jt * 4];
        float av0 = alds[g * 65 + k];
        float av1 = alds[(g + 8) * 65 + k];
        acc[0][0] = fmaf(av0, wv.x, acc[0][0]);
        acc[0][1] = fmaf(av0, wv.y, acc[0][1]);
        acc[0][2] = fmaf(av0, wv.z, acc[0][2]);
        acc[0][3] = fmaf(av0, wv.w, acc[0][3]);
        acc[1][0] = fmaf(av1, wv.x, acc[1][0]);
        acc[1][1] = fmaf(av1, wv.y, acc[1][1]);
        acc[1][2] = fmaf(av1, wv.z, acc[1][2]);
        acc[1][3] = fmaf(av1, wv.w, acc[1][3]);
    }
#pragma unroll
    for (int q = 0; q < 2; ++q) {
        int n = nb + g + q * 8;
        u32 p0 = (u32)f2bf(acc[q][0]) | ((u32)f2bf(acc[q][1]) << 16);
        u32 p1 = (u32)f2bf(acc[q][2]) | ((u32)f2bf(acc[q][3]) << 16);
        *(uint2*)(h2 + (size_t)n * C_OUT + jt * 4) = make_uint2(p0, p1);
    }
}

// ---------- gather2 + bias + relu + mean-pool partials ----------
__global__ __launch_bounds__(256) void k_gather2(const int* __restrict__ rowptr,
                                                 const int* __restrict__ csr_src,
                                                 const float* __restrict__ dinv,
                                                 const u16* __restrict__ h2,
                                                 const float* __restrict__ b2c,
                                                 float* __restrict__ partial) {
    __shared__ float sm[4 * 128];
    int w = threadIdx.x >> 6, lane = threadIdx.x & 63;
    int wid = blockIdx.x * 4 + w;
    float b2A = b2c[2 * lane], b2B = b2c[2 * lane + 1];
    float pA = 0.f, pB = 0.f;
    for (int n = wid; n < N_NODES; n += G2 * 4) {
        int beg = rowptr[n], end = rowptr[n + 1];
        float sA = 0.f, sB = 0.f;
        for (int e = beg; e < end; ++e) {
            int src = csr_src[e];
            float c = dinv[src];
            u32 hp = ((const u32*)(h2 + (size_t)src * C_OUT))[lane];
            sA = fmaf(c, bflo(hp), sA);
            sB = fmaf(c, bfhi(hp), sB);
        }
        float dn = dinv[n];
        u32 hn = ((const u32*)(h2 + (size_t)n * C_OUT))[lane];
        float oA = fmaxf(dn * sA + dn * dn * bflo(hn) + b2A, 0.f);
        float oB = fmaxf(dn * sB + dn * dn * bfhi(hn) + b2B, 0.f);
        pA += oA;
        pB += oB;
    }
    sm[w * 128 + 2 * lane] = pA;
    sm[w * 128 + 2 * lane + 1] = pB;
    __syncthreads();
    int t = threadIdx.x;
    if (t < 128) {
        partial[blockIdx.x * 128 + t] = sm[t] + sm[128 + t] + sm[256 + t] + sm[384 + t];
    }
}

// ---------- final: mean + FC -> 2 outputs (dtype per flag) ----------
__global__ __launch_bounds__(128) void k_final(const float* __restrict__ partial,
                                               const float* __restrict__ fcWc,
                                               const float* __restrict__ fcbc,
                                               void* __restrict__ out,
                                               const int* __restrict__ flags) {
    __shared__ float sm[256];
    int f = threadIdx.x;
    float s = 0.f;
    for (int b = 0; b < G2; ++b) s += partial[b * 128 + f];
    float gm = s * (1.0f / (float)N_NODES);
    sm[f] = gm * fcWc[f];              // fcW[0][f]
    sm[128 + f] = gm * fcWc[128 + f];  // fcW[1][f]
    __syncthreads();
    for (int off = 64; off >= 1; off >>= 1) {
        if (f < off) {
            sm[f] += sm[f + off];
            sm[128 + f] += sm[128 + f + off];
        }
        __syncthreads();
    }
    if (f == 0) {
        float o0 = sm[0] + fcbc[0];
        float o1 = sm[128] + fcbc[1];
        if (flags[0]) {
            u16* ob = (u16*)out;
            ob[0] = f2bf(o0);
            ob[1] = f2bf(o1);
        } else {
            float* of = (float*)out;
            of[0] = o0;
            of[1] = o1;
        }
    }
}

// ---------- workspace layout (bytes, 128-aligned) ----------
#define OFF_FLAGS   0u
#define OFF_DINV    512u        // float[N] (first used as int cnt[N])
#define OFF_ROWPTR  400896u     // int[N+1]
#define OFF_CURSOR  801280u     // int[N]
#define OFF_CSR     1201664u    // int[E]
#define OFF_H1      14001664u   // bf16[N*64]
#define OFF_A1      26801664u   // bf16[N*64]
#define OFF_H2      39601664u   // bf16[N*128]
#define OFF_PART    65201664u   // float[G2*128]
#define OFF_BSUM    65725952u   // int[NBLK_N]
#define OFF_W1C     65728000u   // u16[256*64]
#define OFF_W2C     65760768u   // u16[64*128]
#define OFF_B1C     65777152u   // float[64]
#define OFF_B2C     65777408u   // float[128]
#define OFF_FCWC    65777920u   // float[256]
#define OFF_FCBC    65778944u   // float[2]

extern "C" void kernel_launch(void* const* d_in, const int* in_sizes, int n_in,
                              void* d_out, int out_size, void* d_ws, size_t ws_size,
                              hipStream_t stream) {
    (void)in_sizes; (void)n_in; (void)out_size; (void)ws_size;
    const void* x   = d_in[0];
    const int*  ei  = (const int*)d_in[1];
    const void* W1  = d_in[2];
    const void* b1  = d_in[3];
    const void* W2  = d_in[4];
    const void* b2  = d_in[5];
    const void* fcW = d_in[6];
    const void* fcb = d_in[7];

    char* ws = (char*)d_ws;
    int*   flags  = (int*)(ws + OFF_FLAGS);
    float* dinv   = (float*)(ws + OFF_DINV);
    int*   cnt    = (int*)(ws + OFF_DINV);
    int*   rowptr = (int*)(ws + OFF_ROWPTR);
    int*   cursor = (int*)(ws + OFF_CURSOR);
    int*   csr    = (int*)(ws + OFF_CSR);
    u16*   h1     = (u16*)(ws + OFF_H1);
    u16*   a1     = (u16*)(ws + OFF_A1);
    u16*   h2     = (u16*)(ws + OFF_H2);
    float* partial= (float*)(ws + OFF_PART);
    int*   bsum   = (int*)(ws + OFF_BSUM);
    u16*   W1c    = (u16*)(ws + OFF_W1C);
    u16*   W2c    = (u16*)(ws + OFF_W2C);
    float* b1c    = (float*)(ws + OFF_B1C);
    float* b2c    = (float*)(ws + OFF_B2C);
    float* fcWc   = (float*)(ws + OFF_FCWC);
    float* fcbc   = (float*)(ws + OFF_FCBC);

    k_detect<<<1, 256, 0, stream>>>(x, ei, W1, b1, W2, b2, fcW, fcb,
                                    flags, W1c, W2c, b1c, b2c, fcWc, fcbc);
    k_init<<<NBLK_N, 256, 0, stream>>>(cnt);
    k_count<<<N_EDGES / 256, 256, 0, stream>>>(ei, cnt, flags);
    k_scan1<<<NBLK_N, 256, 0, stream>>>(cnt, rowptr, bsum);
    k_scan2<<<1, 512, 0, stream>>>(bsum);
    k_finalize<<<NBLK_N, 256, 0, stream>>>(rowptr, cursor, cnt, dinv, bsum);
    k_scatter<<<N_EDGES / 256, 256, 0, stream>>>(ei, cursor, csr, flags);
    k_gemm1<<<N_NODES / 16, 256, 0, stream>>>(x, W1c, h1, flags);
    k_gather1<<<N_NODES / 4, 256, 0, stream>>>(rowptr, csr, dinv, h1, b1c, a1);
    k_gemm2<<<N_NODES / 16, 256, 0, stream>>>(a1, W2c, h2);
    k_gather2<<<G2, 256, 0, stream>>>(rowptr, csr, dinv, h2, b2c, partial);
    k_final<<<1, 128, 0, stream>>>(partial, fcWc, fcbc, (void*)d_out, flags);
}

// Round 3
// 914.705 us; speedup vs baseline: 1.4859x; 1.4859x over previous
//
#include <hip/hip_runtime.h>

#define N_NODES 100000
#define N_EDGES 3200000
#define C_IN 256
#define C_H 64
#define C_OUT 128
#define NBLK_N 391   // ceil(N_NODES/256)
#define G2 1024      // blocks for fused gemm2+pool
#define NTILES 6250  // N_NODES/16

typedef unsigned int u32;
typedef unsigned short u16;
typedef unsigned long long u64;

// ---------- bf16 helpers (bf16 = upper 16 bits of fp32) ----------
__device__ __forceinline__ float bflo(u32 p) {
    union { u32 i; float f; } v; v.i = p << 16; return v.f;
}
__device__ __forceinline__ float bfhi(u32 p) {
    union { u32 i; float f; } v; v.i = p & 0xffff0000u; return v.f;
}
__device__ __forceinline__ float bf2f(u16 u) {
    union { u32 i; float f; } v; v.i = ((u32)u) << 16; return v.f;
}
__device__ __forceinline__ u16 f2bf(float f) {
    union { float f; u32 i; } v; v.f = f;
    u32 x = v.i;
    return (u16)((x + 0x7fffu + ((x >> 16) & 1u)) >> 16);  // RNE
}

// ---------- detection + canonicalization ----------
// flags[0] = 1 if float tensors are bf16, 0 if fp32
// flags[1] = 1 if edge_index is int64, 0 if int32
__global__ void k_detect(const void* __restrict__ x, const void* __restrict__ ei,
                         const void* __restrict__ W1, const void* __restrict__ b1,
                         const void* __restrict__ W2, const void* __restrict__ b2,
                         const void* __restrict__ fcW, const void* __restrict__ fcb,
                         int* __restrict__ flags,
                         u16* __restrict__ W1c, u16* __restrict__ W2c,
                         float* __restrict__ b1c, float* __restrict__ b2c,
                         float* __restrict__ fcWc, float* __restrict__ fcbc) {
    __shared__ int sf[2];
    int t = threadIdx.x;
    if (t < 64) {
        u32 w = ((const u32*)x)[t];
        u32 low = w & 0xffffu;
        int e = (int)((low >> 7) & 0xff);
        bool inw = (e > 96 && e < 160) || (low == 0);
        u64 m = __ballot(inw);
        if (t == 0) sf[0] = (__popcll(m) >= 60) ? 1 : 0;
    } else if (t < 128) {
        int i = t - 64;
        u32 w = ((const u32*)ei)[2 * i + 1];   // high dwords if int64
        u64 m = __ballot(w == 0);
        if (i == 0) sf[1] = (m == ~0ull) ? 1 : 0;
    }
    __syncthreads();
    if (t == 0) { flags[0] = sf[0]; flags[1] = sf[1]; }
    int isbf = sf[0];
    if (isbf) {
        const u16* w1 = (const u16*)W1;
        const u16* w2 = (const u16*)W2;
        for (int i = t; i < C_IN * C_H; i += 256) W1c[i] = w1[i];
        for (int i = t; i < C_H * C_OUT; i += 256) W2c[i] = w2[i];
        const u16* p1 = (const u16*)b1;  const u16* p2 = (const u16*)b2;
        const u16* pw = (const u16*)fcW; const u16* pb = (const u16*)fcb;
        for (int i = t; i < C_H; i += 256) b1c[i] = bf2f(p1[i]);
        for (int i = t; i < C_OUT; i += 256) b2c[i] = bf2f(p2[i]);
        for (int i = t; i < 2 * C_OUT; i += 256) fcWc[i] = bf2f(pw[i]);
        for (int i = t; i < 2; i += 256) fcbc[i] = bf2f(pb[i]);
    } else {
        const float* w1 = (const float*)W1;
        const float* w2 = (const float*)W2;
        for (int i = t; i < C_IN * C_H; i += 256) W1c[i] = f2bf(w1[i]);
        for (int i = t; i < C_H * C_OUT; i += 256) W2c[i] = f2bf(w2[i]);
        const float* p1 = (const float*)b1;  const float* p2 = (const float*)b2;
        const float* pw = (const float*)fcW; const float* pb = (const float*)fcb;
        for (int i = t; i < C_H; i += 256) b1c[i] = p1[i];
        for (int i = t; i < C_OUT; i += 256) b2c[i] = p2[i];
        for (int i = t; i < 2 * C_OUT; i += 256) fcWc[i] = pw[i];
        for (int i = t; i < 2; i += 256) fcbc[i] = pb[i];
    }
}

// ---------- CSR build ----------
__global__ void k_init(int* __restrict__ cnt) {
    int i = blockIdx.x * 256 + threadIdx.x;
    if (i < N_NODES) cnt[i] = 0;
}

__global__ void k_count(const int* __restrict__ ei, int* __restrict__ cnt,
                        const int* __restrict__ flags) {
    int is64 = flags[1];
    int e = blockIdx.x * 256 + threadIdx.x;
    if (e < N_EDGES) {
        int d = is64 ? ei[2 * (N_EDGES + e)] : ei[N_EDGES + e];
        atomicAdd(&cnt[d], 1);
    }
}

__global__ void k_scan1(const int* __restrict__ cnt, int* __restrict__ rowptr,
                        int* __restrict__ bsum) {
    __shared__ int sm[256];
    int t = threadIdx.x;
    int i = blockIdx.x * 256 + t;
    int v = (i < N_NODES) ? cnt[i] : 0;
    sm[t] = v;
    __syncthreads();
    for (int off = 1; off < 256; off <<= 1) {
        int add = (t >= off) ? sm[t - off] : 0;
        __syncthreads();
        sm[t] += add;
        __syncthreads();
    }
    if (i < N_NODES) rowptr[i] = sm[t] - v;      // exclusive
    if (t == 255) bsum[blockIdx.x] = sm[255];    // inclusive total
}

__global__ void k_scan2(int* __restrict__ bsum) {
    __shared__ int sm[512];
    int t = threadIdx.x;
    int v = (t < NBLK_N) ? bsum[t] : 0;
    sm[t] = v;
    __syncthreads();
    for (int off = 1; off < 512; off <<= 1) {
        int add = (t >= off) ? sm[t - off] : 0;
        __syncthreads();
        sm[t] += add;
        __syncthreads();
    }
    if (t < NBLK_N) bsum[t] = sm[t] - v;
}

__global__ void k_finalize(int* __restrict__ rowptr, int* __restrict__ cursor,
                           int* cnt, float* dinv, const int* __restrict__ bsum) {
    int i = blockIdx.x * 256 + threadIdx.x;
    if (i < N_NODES) {
        int rp = rowptr[i] + bsum[blockIdx.x];
        rowptr[i] = rp;
        cursor[i] = rp;
        int deg = cnt[i] + 1;
        dinv[i] = rsqrtf((float)deg);
    }
    if (i == 0) rowptr[N_NODES] = N_EDGES;
}

__global__ void k_scatter(const int* __restrict__ ei, int* __restrict__ cursor,
                          int* __restrict__ csr_src, const int* __restrict__ flags) {
    int is64 = flags[1];
    int e = blockIdx.x * 256 + threadIdx.x;
    if (e < N_EDGES) {
        int s = is64 ? ei[2 * e] : ei[e];
        int d = is64 ? ei[2 * (N_EDGES + e)] : ei[N_EDGES + e];
        int p = atomicAdd(&cursor[d], 1);
        csr_src[p] = s;
    }
}

// ---------- GEMM1: h1[N,64] = x[N,256] @ W1[256,64] (fp32 acc, bf16 out) ----------
__global__ __launch_bounds__(256) void k_gemm1(const void* __restrict__ xv,
                                               const u16* __restrict__ W1c,
                                               u16* __restrict__ h1,
                                               const int* __restrict__ flags) {
    __shared__ u32 wlds[C_IN * C_H / 2];   // packed bf16x2, 32KB
    __shared__ float xlds[16 * 257];
    int t = threadIdx.x;
    int nb = blockIdx.x * 16;
    int isbf = flags[0];

    const u32* w32 = (const u32*)W1c;
#pragma unroll
    for (int it = 0; it < 32; ++it) wlds[t + it * 256] = w32[t + it * 256];

    if (isbf) {
        const u32* x32 = (const u32*)xv + (size_t)nb * (C_IN / 2);
#pragma unroll
        for (int it = 0; it < 8; ++it) {
            int d = t + it * 256;
            u32 pk = x32[d];
            int e0 = d * 2;
            int r = e0 >> 8, c = e0 & 255;
            float* dst = &xlds[r * 257 + c];
            dst[0] = bflo(pk);
            dst[1] = bfhi(pk);
        }
    } else {
        const float* xf = (const float*)xv + (size_t)nb * C_IN;
#pragma unroll
        for (int it = 0; it < 16; ++it) {
            int e = t + it * 256;
            int r = e >> 8, c = e & 255;
            xlds[r * 257 + c] = xf[e];
        }
    }
    __syncthreads();

    int jt = t & 15, nl = t >> 4;
    const float* xr = &xlds[nl * 257];
    float a0 = 0.f, a1 = 0.f, a2 = 0.f, a3 = 0.f;
#pragma unroll 4
    for (int k = 0; k < C_IN; ++k) {
        float xvv = xr[k];
        uint2 wp = *(const uint2*)&wlds[k * 32 + jt * 2];
        a0 = fmaf(xvv, bflo(wp.x), a0);
        a1 = fmaf(xvv, bfhi(wp.x), a1);
        a2 = fmaf(xvv, bflo(wp.y), a2);
        a3 = fmaf(xvv, bfhi(wp.y), a3);
    }
    int n = nb + nl;
    u32 p0 = (u32)f2bf(a0) | ((u32)f2bf(a1) << 16);
    u32 p1 = (u32)f2bf(a2) | ((u32)f2bf(a3) << 16);
    *(uint2*)(h1 + n * C_H + jt * 4) = make_uint2(p0, p1);
}

// ---------- unified gather over a 64-channel bf16 table ----------
// One wave per node. Lanes split in two halves of 32; each half walks alternate
// edges (unrolled x2 => 4 independent 128B row-loads in flight per wave).
// Lane j (j = lane&31) covers channels 2j, 2j+1 (one u32 = 2 bf16).
// MODE 0: out = bf16( relu(dn*s + dn^2*h[n] + bias) )   (layer-1 activation)
// MODE 1: out = fp32( dn*s + dn^2*h[n] )                 (layer-2 pre-GEMM agg)
template <int MODE>
__global__ __launch_bounds__(256) void k_gatherT(const int* __restrict__ rowptr,
                                                 const int* __restrict__ csr_src,
                                                 const float* __restrict__ dinv,
                                                 const u16* __restrict__ h,
                                                 const float* __restrict__ bias,
                                                 void* __restrict__ outv) {
    int w = threadIdx.x >> 6, lane = threadIdx.x & 63;
    int n = blockIdx.x * 4 + w;
    if (n >= N_NODES) return;
    int j = lane & 31;
    int half = lane >> 5;
    int beg = rowptr[n], end = rowptr[n + 1];
    float sA = 0.f, sB = 0.f;
    int e = beg + half;
    for (; e + 2 < end; e += 4) {
        int s0 = csr_src[e];
        int s1 = csr_src[e + 2];
        float c0 = dinv[s0];
        float c1 = dinv[s1];
        u32 p0 = *(const u32*)(h + s0 * C_H + 2 * j);
        u32 p1 = *(const u32*)(h + s1 * C_H + 2 * j);
        sA = fmaf(c0, bflo(p0), sA);
        sB = fmaf(c0, bfhi(p0), sB);
        sA = fmaf(c1, bflo(p1), sA);
        sB = fmaf(c1, bfhi(p1), sB);
    }
    if (e < end) {
        int s0 = csr_src[e];
        float c0 = dinv[s0];
        u32 p0 = *(const u32*)(h + s0 * C_H + 2 * j);
        sA = fmaf(c0, bflo(p0), sA);
        sB = fmaf(c0, bfhi(p0), sB);
    }
    // combine the two halves (lane ^ 32)
    sA += __shfl_xor(sA, 32, 64);
    sB += __shfl_xor(sB, 32, 64);

    float dn = dinv[n];
    u32 hn = *(const u32*)(h + n * C_H + 2 * j);
    float oA = dn * sA + dn * dn * bflo(hn);
    float oB = dn * sB + dn * dn * bfhi(hn);
    if (MODE == 0) {
        oA = fmaxf(oA + bias[2 * j], 0.f);
        oB = fmaxf(oB + bias[2 * j + 1], 0.f);
        if (half == 0) {
            u32 pk = (u32)f2bf(oA) | ((u32)f2bf(oB) << 16);
            ((u32*)outv)[n * 32 + j] = pk;
        }
    } else {
        if (half == 0) {
            ((float2*)outv)[n * 32 + j] = make_float2(oA, oB);
        }
    }
}

// ---------- fused GEMM2 + bias + relu + mean-pool partials ----------
// h2 = agg[N,64] @ W2[64,128] + b2; a2 = relu(h2); partial[b] = sum over nodes.
__global__ __launch_bounds__(256) void k_fused2(const float* __restrict__ agg,
                                                const u16* __restrict__ W2c,
                                                const float* __restrict__ b2c,
                                                float* __restrict__ partial) {
    __shared__ float wlds[C_H * C_OUT];   // 32KB fp32 W2
    __shared__ float alds[16 * 65];       // 16 nodes x 64 (stride 65)
    __shared__ float psum[256 * 4];       // pool reduce buffer
    int t = threadIdx.x;

    const u32* w32 = (const u32*)W2c;     // 4096 dwords
#pragma unroll
    for (int it = 0; it < 16; ++it) {
        int d = t + it * 256;
        u32 pk = w32[d];
        int e0 = d * 2;
        wlds[e0] = bflo(pk);
        wlds[e0 + 1] = bfhi(pk);
    }
    int jt = t & 31, g = t >> 5;
    float bias0 = b2c[jt * 4 + 0], bias1 = b2c[jt * 4 + 1];
    float bias2 = b2c[jt * 4 + 2], bias3 = b2c[jt * 4 + 3];
    float pacc[4] = {0.f, 0.f, 0.f, 0.f};

    for (int tile = blockIdx.x; tile < NTILES; tile += G2) {
        __syncthreads();
        {   // stage 16x64 fp32 agg tile
            const float* src = agg + (size_t)tile * 16 * C_H;
            int d = t * 4;
            float4 v = *(const float4*)(src + d);
            int r = d >> 6, c = d & 63;
            float* dst = &alds[r * 65 + c];
            dst[0] = v.x; dst[1] = v.y; dst[2] = v.z; dst[3] = v.w;
        }
        __syncthreads();
        float acc[2][4] = {{0.f, 0.f, 0.f, 0.f}, {0.f, 0.f, 0.f, 0.f}};
#pragma unroll 4
        for (int k = 0; k < C_H; ++k) {
            float4 wv = *(const float4*)&wlds[k * C_OUT + jt * 4];
            float av0 = alds[g * 65 + k];
            float av1 = alds[(g + 8) * 65 + k];
            acc[0][0] = fmaf(av0, wv.x, acc[0][0]);
            acc[0][1] = fmaf(av0, wv.y, acc[0][1]);
            acc[0][2] = fmaf(av0, wv.z, acc[0][2]);
            acc[0][3] = fmaf(av0, wv.w, acc[0][3]);
            acc[1][0] = fmaf(av1, wv.x, acc[1][0]);
            acc[1][1] = fmaf(av1, wv.y, acc[1][1]);
            acc[1][2] = fmaf(av1, wv.z, acc[1][2]);
            acc[1][3] = fmaf(av1, wv.w, acc[1][3]);
        }
#pragma unroll
        for (int q = 0; q < 2; ++q) {
            pacc[0] += fmaxf(acc[q][0] + bias0, 0.f);
            pacc[1] += fmaxf(acc[q][1] + bias1, 0.f);
            pacc[2] += fmaxf(acc[q][2] + bias2, 0.f);
            pacc[3] += fmaxf(acc[q][3] + bias3, 0.f);
        }
    }
    psum[t * 4 + 0] = pacc[0];
    psum[t * 4 + 1] = pacc[1];
    psum[t * 4 + 2] = pacc[2];
    psum[t * 4 + 3] = pacc[3];
    __syncthreads();
    if (t < 32) {
#pragma unroll
        for (int i = 0; i < 4; ++i) {
            float s = 0.f;
#pragma unroll
            for (int gg = 0; gg < 8; ++gg) s += psum[(gg * 32 + t) * 4 + i];
            partial[blockIdx.x * C_OUT + t * 4 + i] = s;
        }
    }
}

// ---------- final: mean + FC -> 2 outputs (dtype per flag) ----------
__global__ __launch_bounds__(128) void k_final(const float* __restrict__ partial,
                                               const float* __restrict__ fcWc,
                                               const float* __restrict__ fcbc,
                                               void* __restrict__ out,
                                               const int* __restrict__ flags) {
    __shared__ float sm[256];
    int f = threadIdx.x;
    float s = 0.f;
    for (int b = 0; b < G2; ++b) s += partial[b * 128 + f];
    float gm = s * (1.0f / (float)N_NODES);
    sm[f] = gm * fcWc[f];
    sm[128 + f] = gm * fcWc[128 + f];
    __syncthreads();
    for (int off = 64; off >= 1; off >>= 1) {
        if (f < off) {
            sm[f] += sm[f + off];
            sm[128 + f] += sm[128 + f + off];
        }
        __syncthreads();
    }
    if (f == 0) {
        float o0 = sm[0] + fcbc[0];
        float o1 = sm[128] + fcbc[1];
        if (flags[0]) {
            u16* ob = (u16*)out;
            ob[0] = f2bf(o0);
            ob[1] = f2bf(o1);
        } else {
            float* of = (float*)out;
            of[0] = o0;
            of[1] = o1;
        }
    }
}

// ---------- workspace layout (bytes, 128-aligned) ----------
#define OFF_FLAGS   0u
#define OFF_DINV    512u        // float[N] (first used as int cnt[N])
#define OFF_ROWPTR  400896u     // int[N+1]
#define OFF_CURSOR  801280u     // int[N]
#define OFF_CSR     1201664u    // int[E]
#define OFF_H1      14001664u   // bf16[N*64]
#define OFF_A1      26801664u   // bf16[N*64]
#define OFF_AGG     39601664u   // float[N*64]  (25.6MB)
#define OFF_PART    65201664u   // float[G2*128]
#define OFF_BSUM    65725952u   // int[NBLK_N]
#define OFF_W1C     65728000u   // u16[256*64]
#define OFF_W2C     65760768u   // u16[64*128]
#define OFF_B1C     65777152u   // float[64]
#define OFF_B2C     65777408u   // float[128]
#define OFF_FCWC    65777920u   // float[256]
#define OFF_FCBC    65778944u   // float[2]

extern "C" void kernel_launch(void* const* d_in, const int* in_sizes, int n_in,
                              void* d_out, int out_size, void* d_ws, size_t ws_size,
                              hipStream_t stream) {
    (void)in_sizes; (void)n_in; (void)out_size; (void)ws_size;
    const void* x   = d_in[0];
    const int*  ei  = (const int*)d_in[1];
    const void* W1  = d_in[2];
    const void* b1  = d_in[3];
    const void* W2  = d_in[4];
    const void* b2  = d_in[5];
    const void* fcW = d_in[6];
    const void* fcb = d_in[7];

    char* ws = (char*)d_ws;
    int*   flags  = (int*)(ws + OFF_FLAGS);
    float* dinv   = (float*)(ws + OFF_DINV);
    int*   cnt    = (int*)(ws + OFF_DINV);
    int*   rowptr = (int*)(ws + OFF_ROWPTR);
    int*   cursor = (int*)(ws + OFF_CURSOR);
    int*   csr    = (int*)(ws + OFF_CSR);
    u16*   h1     = (u16*)(ws + OFF_H1);
    u16*   a1     = (u16*)(ws + OFF_A1);
    float* agg    = (float*)(ws + OFF_AGG);
    float* partial= (float*)(ws + OFF_PART);
    int*   bsum   = (int*)(ws + OFF_BSUM);
    u16*   W1c    = (u16*)(ws + OFF_W1C);
    u16*   W2c    = (u16*)(ws + OFF_W2C);
    float* b1c    = (float*)(ws + OFF_B1C);
    float* b2c    = (float*)(ws + OFF_B2C);
    float* fcWc   = (float*)(ws + OFF_FCWC);
    float* fcbc   = (float*)(ws + OFF_FCBC);

    k_detect<<<1, 256, 0, stream>>>(x, ei, W1, b1, W2, b2, fcW, fcb,
                                    flags, W1c, W2c, b1c, b2c, fcWc, fcbc);
    k_init<<<NBLK_N, 256, 0, stream>>>(cnt);
    k_count<<<N_EDGES / 256, 256, 0, stream>>>(ei, cnt, flags);
    k_scan1<<<NBLK_N, 256, 0, stream>>>(cnt, rowptr, bsum);
    k_scan2<<<1, 512, 0, stream>>>(bsum);
    k_finalize<<<NBLK_N, 256, 0, stream>>>(rowptr, cursor, cnt, dinv, bsum);
    k_scatter<<<N_EDGES / 256, 256, 0, stream>>>(ei, cursor, csr, flags);
    k_gemm1<<<N_NODES / 16, 256, 0, stream>>>(x, W1c, h1, flags);
    k_gatherT<0><<<N_NODES / 4, 256, 0, stream>>>(rowptr, csr, dinv, h1, b1c, (void*)a1);
    k_gatherT<1><<<N_NODES / 4, 256, 0, stream>>>(rowptr, csr, dinv, a1, (const float*)nullptr, (void*)agg);
    k_fused2<<<G2, 256, 0, stream>>>(agg, W2c, b2c, partial);
    k_final<<<1, 128, 0, stream>>>(partial, fcWc, fcbc, (void*)d_out, flags);
}

// Round 4
// 581.480 us; speedup vs baseline: 2.3375x; 1.5731x over previous
//
#include <hip/hip_runtime.h>

#define N_NODES 100000
#define N_EDGES 3200000
#define C_IN 256
#define C_H 64
#define C_OUT 128
#define NB 391       // ceil(N_NODES/256) buckets of 256 nodes
#define G2 1024      // blocks for fused gemm2+pool
#define NTILES 6250  // N_NODES/16
#define CH1 8192     // edges per block in hist/scatter1

typedef unsigned int u32;
typedef unsigned short u16;
typedef unsigned long long u64;

// ---------- bf16 helpers ----------
__device__ __forceinline__ float bflo(u32 p) {
    union { u32 i; float f; } v; v.i = p << 16; return v.f;
}
__device__ __forceinline__ float bfhi(u32 p) {
    union { u32 i; float f; } v; v.i = p & 0xffff0000u; return v.f;
}
__device__ __forceinline__ float bf2f(u16 u) {
    union { u32 i; float f; } v; v.i = ((u32)u) << 16; return v.f;
}
__device__ __forceinline__ u16 f2bf(float f) {
    union { float f; u32 i; } v; v.f = f;
    u32 x = v.i;
    return (u16)((x + 0x7fffu + ((x >> 16) & 1u)) >> 16);  // RNE
}

// ---------- detection + canonicalization ----------
__global__ void k_detect(const void* __restrict__ x, const void* __restrict__ ei,
                         const void* __restrict__ W1, const void* __restrict__ b1,
                         const void* __restrict__ W2, const void* __restrict__ b2,
                         const void* __restrict__ fcW, const void* __restrict__ fcb,
                         int* __restrict__ flags,
                         u16* __restrict__ W1c, u16* __restrict__ W2c,
                         float* __restrict__ b1c, float* __restrict__ b2c,
                         float* __restrict__ fcWc, float* __restrict__ fcbc,
                         u32* __restrict__ bucket_cnt) {
    __shared__ int sf[2];
    int t = threadIdx.x;
    if (t < 64) {
        u32 w = ((const u32*)x)[t];
        u32 low = w & 0xffffu;
        int e = (int)((low >> 7) & 0xff);
        bool inw = (e > 96 && e < 160) || (low == 0);
        u64 m = __ballot(inw);
        if (t == 0) sf[0] = (__popcll(m) >= 60) ? 1 : 0;
    } else if (t < 128) {
        int i = t - 64;
        u32 w = ((const u32*)ei)[2 * i + 1];   // high dwords if int64
        u64 m = __ballot(w == 0);
        if (i == 0) sf[1] = (m == ~0ull) ? 1 : 0;
    }
    __syncthreads();
    if (t == 0) { flags[0] = sf[0]; flags[1] = sf[1]; }
    for (int i = t; i < NB; i += 256) bucket_cnt[i] = 0;
    int isbf = sf[0];
    if (isbf) {
        const u16* w1 = (const u16*)W1;
        const u16* w2 = (const u16*)W2;
        for (int i = t; i < C_IN * C_H; i += 256) W1c[i] = w1[i];
        for (int i = t; i < C_H * C_OUT; i += 256) W2c[i] = w2[i];
        const u16* p1 = (const u16*)b1;  const u16* p2 = (const u16*)b2;
        const u16* pw = (const u16*)fcW; const u16* pb = (const u16*)fcb;
        for (int i = t; i < C_H; i += 256) b1c[i] = bf2f(p1[i]);
        for (int i = t; i < C_OUT; i += 256) b2c[i] = bf2f(p2[i]);
        for (int i = t; i < 2 * C_OUT; i += 256) fcWc[i] = bf2f(pw[i]);
        for (int i = t; i < 2; i += 256) fcbc[i] = bf2f(pb[i]);
    } else {
        const float* w1 = (const float*)W1;
        const float* w2 = (const float*)W2;
        for (int i = t; i < C_IN * C_H; i += 256) W1c[i] = f2bf(w1[i]);
        for (int i = t; i < C_H * C_OUT; i += 256) W2c[i] = f2bf(w2[i]);
        const float* p1 = (const float*)b1;  const float* p2 = (const float*)b2;
        const float* pw = (const float*)fcW; const float* pb = (const float*)fcb;
        for (int i = t; i < C_H; i += 256) b1c[i] = p1[i];
        for (int i = t; i < C_OUT; i += 256) b2c[i] = p2[i];
        for (int i = t; i < 2 * C_OUT; i += 256) fcWc[i] = pw[i];
        for (int i = t; i < 2; i += 256) fcbc[i] = pb[i];
    }
}

// ---------- bucket histogram over dst>>8 ----------
__global__ __launch_bounds__(256) void k_hist1(const int* __restrict__ ei,
                                               const int* __restrict__ flags,
                                               u32* __restrict__ bucket_cnt) {
    __shared__ u32 h[NB];
    int t = threadIdx.x;
    int is64 = flags[1];
    for (int i = t; i < NB; i += 256) h[i] = 0;
    __syncthreads();
    int e0 = blockIdx.x * CH1;
    int nv = min(CH1, N_EDGES - e0);
    for (int i = t; i < nv; i += 256) {
        int e = e0 + i;
        int d = is64 ? ei[2 * (N_EDGES + e)] : ei[N_EDGES + e];
        atomicAdd(&h[d >> 8], 1u);
    }
    __syncthreads();
    for (int i = t; i < NB; i += 256)
        if (h[i]) atomicAdd(&bucket_cnt[i], h[i]);
}

// ---------- scan bucket counts -> base + cursor ----------
__global__ __launch_bounds__(512) void k_bscan(const u32* __restrict__ bucket_cnt,
                                               u32* __restrict__ bucket_base,
                                               u32* __restrict__ bucket_cursor,
                                               int* __restrict__ rowptr) {
    __shared__ u32 sm[512];
    int t = threadIdx.x;
    u32 v = (t < NB) ? bucket_cnt[t] : 0;
    sm[t] = v;
    __syncthreads();
    for (int off = 1; off < 512; off <<= 1) {
        u32 a = (t >= off) ? sm[t - off] : 0;
        __syncthreads();
        sm[t] += a;
        __syncthreads();
    }
    if (t < NB) {
        u32 excl = sm[t] - v;
        bucket_base[t] = excl;
        bucket_cursor[t] = excl;
    }
    if (t == 0) {
        bucket_base[NB] = N_EDGES;
        rowptr[N_NODES] = N_EDGES;
    }
}

// ---------- pass 1: bucket-sorted staged scatter (line-dense writes) ----------
__global__ __launch_bounds__(512) void k_scatter1(const int* __restrict__ ei,
                                                  const int* __restrict__ flags,
                                                  u32* __restrict__ bucket_cursor,
                                                  u32* __restrict__ ebuf) {
    __shared__ u32 cnt[NB];
    __shared__ u32 lcur[NB];
    __shared__ u32 gbase[NB];
    __shared__ u32 lofs[512];
    __shared__ u32 stp[CH1];
    __shared__ u16 stb[CH1];
    int t = threadIdx.x;
    int is64 = flags[1];
    int e0 = blockIdx.x * CH1;
    int nv = min(CH1, N_EDGES - e0);
    for (int i = t; i < NB; i += 512) { cnt[i] = 0; lcur[i] = 0; }
    __syncthreads();
    // phase 1: count
    for (int i = t; i < nv; i += 512) {
        int e = e0 + i;
        int d = is64 ? ei[2 * (N_EDGES + e)] : ei[N_EDGES + e];
        atomicAdd(&cnt[d >> 8], 1u);
    }
    __syncthreads();
    // phase 2: exclusive scan of cnt -> lofs
    u32 v = (t < NB) ? cnt[t] : 0;
    lofs[t] = v;
    __syncthreads();
    for (int off = 1; off < 512; off <<= 1) {
        u32 a = (t >= off) ? lofs[t - off] : 0;
        __syncthreads();
        lofs[t] += a;
        __syncthreads();
    }
    u32 excl = lofs[t] - v;
    __syncthreads();
    lofs[t] = excl;
    __syncthreads();
    // phase 3: place into staged arrays (bucket-sorted)
    for (int i = t; i < nv; i += 512) {
        int e = e0 + i;
        int d, s;
        if (is64) { d = ei[2 * (N_EDGES + e)]; s = ei[2 * e]; }
        else      { d = ei[N_EDGES + e];       s = ei[e]; }
        int b = d >> 8;
        u32 slot = lofs[b] + atomicAdd(&lcur[b], 1u);
        stp[slot] = ((u32)(d & 255) << 20) | (u32)s;
        stb[slot] = (u16)b;
    }
    __syncthreads();
    // phase 4: reserve global space per bucket
    for (int b = t; b < NB; b += 512) {
        u32 c = cnt[b];
        gbase[b] = c ? atomicAdd(&bucket_cursor[b], c) : 0;
    }
    __syncthreads();
    // phase 5: write out (consecutive slots -> mostly consecutive addrs)
    for (int s = t; s < nv; s += 512) {
        int b = stb[s];
        ebuf[gbase[b] + (s - lofs[b])] = stp[s];
    }
}

// ---------- pass 2: per-bucket local sort -> csr + rowptr + dinv ----------
__global__ __launch_bounds__(256) void k_scatter2(const u32* __restrict__ bucket_base,
                                                  const u32* __restrict__ ebuf,
                                                  int* __restrict__ rowptr,
                                                  float* __restrict__ dinv,
                                                  int* __restrict__ csr) {
    __shared__ int cnt[256];
    __shared__ int pfx[256];
    __shared__ int lcur[256];
    int b = blockIdx.x, t = threadIdx.x;
    int ebeg = (int)bucket_base[b], eend = (int)bucket_base[b + 1];
    cnt[t] = 0;
    lcur[t] = 0;
    __syncthreads();
    for (int i = ebeg + t; i < eend; i += 256)
        atomicAdd(&cnt[(ebuf[i] >> 20) & 255], 1);
    __syncthreads();
    int v = cnt[t];
    pfx[t] = v;
    __syncthreads();
    for (int off = 1; off < 256; off <<= 1) {
        int a = (t >= off) ? pfx[t - off] : 0;
        __syncthreads();
        pfx[t] += a;
        __syncthreads();
    }
    int node = (b << 8) + t;
    if (node < N_NODES) {
        rowptr[node] = ebeg + (pfx[t] - v);
        dinv[node] = rsqrtf((float)(v + 1));
    }
    __syncthreads();
    for (int i = ebeg + t; i < eend; i += 256) {
        u32 p = ebuf[i];
        int dl = (p >> 20) & 255;
        int pos = ebeg + (pfx[dl] - cnt[dl]) + atomicAdd(&lcur[dl], 1);
        csr[pos] = (int)(p & 0x1FFFFu);
    }
}

// ---------- GEMM1: h1[N,64] = x[N,256] @ W1[256,64] ----------
__global__ __launch_bounds__(256) void k_gemm1(const void* __restrict__ xv,
                                               const u16* __restrict__ W1c,
                                               u16* __restrict__ h1,
                                               const int* __restrict__ flags) {
    __shared__ u32 wlds[C_IN * C_H / 2];
    __shared__ float xlds[16 * 257];
    int t = threadIdx.x;
    int nb = blockIdx.x * 16;
    int isbf = flags[0];

    const u32* w32 = (const u32*)W1c;
#pragma unroll
    for (int it = 0; it < 32; ++it) wlds[t + it * 256] = w32[t + it * 256];

    if (isbf) {
        const u32* x32 = (const u32*)xv + (size_t)nb * (C_IN / 2);
#pragma unroll
        for (int it = 0; it < 8; ++it) {
            int d = t + it * 256;
            u32 pk = x32[d];
            int e0 = d * 2;
            int r = e0 >> 8, c = e0 & 255;
            float* dst = &xlds[r * 257 + c];
            dst[0] = bflo(pk);
            dst[1] = bfhi(pk);
        }
    } else {
        const float* xf = (const float*)xv + (size_t)nb * C_IN;
#pragma unroll
        for (int it = 0; it < 16; ++it) {
            int e = t + it * 256;
            int r = e >> 8, c = e & 255;
            xlds[r * 257 + c] = xf[e];
        }
    }
    __syncthreads();

    int jt = t & 15, nl = t >> 4;
    const float* xr = &xlds[nl * 257];
    float a0 = 0.f, a1 = 0.f, a2 = 0.f, a3 = 0.f;
#pragma unroll 4
    for (int k = 0; k < C_IN; ++k) {
        float xvv = xr[k];
        uint2 wp = *(const uint2*)&wlds[k * 32 + jt * 2];
        a0 = fmaf(xvv, bflo(wp.x), a0);
        a1 = fmaf(xvv, bfhi(wp.x), a1);
        a2 = fmaf(xvv, bflo(wp.y), a2);
        a3 = fmaf(xvv, bfhi(wp.y), a3);
    }
    int n = nb + nl;
    u32 p0 = (u32)f2bf(a0) | ((u32)f2bf(a1) << 16);
    u32 p1 = (u32)f2bf(a2) | ((u32)f2bf(a3) << 16);
    *(uint2*)(h1 + n * C_H + jt * 4) = make_uint2(p0, p1);
}

// ---------- unified gather over a 64-channel bf16 table ----------
template <int MODE>
__global__ __launch_bounds__(256) void k_gatherT(const int* __restrict__ rowptr,
                                                 const int* __restrict__ csr_src,
                                                 const float* __restrict__ dinv,
                                                 const u16* __restrict__ h,
                                                 const float* __restrict__ bias,
                                                 void* __restrict__ outv) {
    int w = threadIdx.x >> 6, lane = threadIdx.x & 63;
    int n = blockIdx.x * 4 + w;
    if (n >= N_NODES) return;
    int j = lane & 31;
    int half = lane >> 5;
    int beg = rowptr[n], end = rowptr[n + 1];
    float sA = 0.f, sB = 0.f;
    int e = beg + half;
    for (; e + 2 < end; e += 4) {
        int s0 = csr_src[e];
        int s1 = csr_src[e + 2];
        float c0 = dinv[s0];
        float c1 = dinv[s1];
        u32 p0 = *(const u32*)(h + s0 * C_H + 2 * j);
        u32 p1 = *(const u32*)(h + s1 * C_H + 2 * j);
        sA = fmaf(c0, bflo(p0), sA);
        sB = fmaf(c0, bfhi(p0), sB);
        sA = fmaf(c1, bflo(p1), sA);
        sB = fmaf(c1, bfhi(p1), sB);
    }
    if (e < end) {
        int s0 = csr_src[e];
        float c0 = dinv[s0];
        u32 p0 = *(const u32*)(h + s0 * C_H + 2 * j);
        sA = fmaf(c0, bflo(p0), sA);
        sB = fmaf(c0, bfhi(p0), sB);
    }
    sA += __shfl_xor(sA, 32, 64);
    sB += __shfl_xor(sB, 32, 64);

    float dn = dinv[n];
    u32 hn = *(const u32*)(h + n * C_H + 2 * j);
    float oA = dn * sA + dn * dn * bflo(hn);
    float oB = dn * sB + dn * dn * bfhi(hn);
    if (MODE == 0) {
        oA = fmaxf(oA + bias[2 * j], 0.f);
        oB = fmaxf(oB + bias[2 * j + 1], 0.f);
        if (half == 0) {
            u32 pk = (u32)f2bf(oA) | ((u32)f2bf(oB) << 16);
            ((u32*)outv)[n * 32 + j] = pk;
        }
    } else {
        if (half == 0) {
            ((float2*)outv)[n * 32 + j] = make_float2(oA, oB);
        }
    }
}

// ---------- fused GEMM2 + bias + relu + mean-pool partials ----------
__global__ __launch_bounds__(256) void k_fused2(const float* __restrict__ agg,
                                                const u16* __restrict__ W2c,
                                                const float* __restrict__ b2c,
                                                float* __restrict__ partial) {
    __shared__ float wlds[C_H * C_OUT];
    __shared__ float alds[16 * 65];
    __shared__ float psum[256 * 4];
    int t = threadIdx.x;

    const u32* w32 = (const u32*)W2c;
#pragma unroll
    for (int it = 0; it < 16; ++it) {
        int d = t + it * 256;
        u32 pk = w32[d];
        int e0 = d * 2;
        wlds[e0] = bflo(pk);
        wlds[e0 + 1] = bfhi(pk);
    }
    int jt = t & 31, g = t >> 5;
    float bias0 = b2c[jt * 4 + 0], bias1 = b2c[jt * 4 + 1];
    float bias2 = b2c[jt * 4 + 2], bias3 = b2c[jt * 4 + 3];
    float pacc[4] = {0.f, 0.f, 0.f, 0.f};

    for (int tile = blockIdx.x; tile < NTILES; tile += G2) {
        __syncthreads();
        {
            const float* src = agg + (size_t)tile * 16 * C_H;
            int d = t * 4;
            float4 v = *(const float4*)(src + d);
            int r = d >> 6, c = d & 63;
            float* dst = &alds[r * 65 + c];
            dst[0] = v.x; dst[1] = v.y; dst[2] = v.z; dst[3] = v.w;
        }
        __syncthreads();
        float acc[2][4] = {{0.f, 0.f, 0.f, 0.f}, {0.f, 0.f, 0.f, 0.f}};
#pragma unroll 4
        for (int k = 0; k < C_H; ++k) {
            float4 wv = *(const float4*)&wlds[k * C_OUT + jt * 4];
            float av0 = alds[g * 65 + k];
            float av1 = alds[(g + 8) * 65 + k];
            acc[0][0] = fmaf(av0, wv.x, acc[0][0]);
            acc[0][1] = fmaf(av0, wv.y, acc[0][1]);
            acc[0][2] = fmaf(av0, wv.z, acc[0][2]);
            acc[0][3] = fmaf(av0, wv.w, acc[0][3]);
            acc[1][0] = fmaf(av1, wv.x, acc[1][0]);
            acc[1][1] = fmaf(av1, wv.y, acc[1][1]);
            acc[1][2] = fmaf(av1, wv.z, acc[1][2]);
            acc[1][3] = fmaf(av1, wv.w, acc[1][3]);
        }
#pragma unroll
        for (int q = 0; q < 2; ++q) {
            pacc[0] += fmaxf(acc[q][0] + bias0, 0.f);
            pacc[1] += fmaxf(acc[q][1] + bias1, 0.f);
            pacc[2] += fmaxf(acc[q][2] + bias2, 0.f);
            pacc[3] += fmaxf(acc[q][3] + bias3, 0.f);
        }
    }
    psum[t * 4 + 0] = pacc[0];
    psum[t * 4 + 1] = pacc[1];
    psum[t * 4 + 2] = pacc[2];
    psum[t * 4 + 3] = pacc[3];
    __syncthreads();
    if (t < 32) {
#pragma unroll
        for (int i = 0; i < 4; ++i) {
            float s = 0.f;
#pragma unroll
            for (int gg = 0; gg < 8; ++gg) s += psum[(gg * 32 + t) * 4 + i];
            partial[blockIdx.x * C_OUT + t * 4 + i] = s;
        }
    }
}

// ---------- final: mean + FC -> 2 outputs (dtype per flag) ----------
__global__ __launch_bounds__(128) void k_final(const float* __restrict__ partial,
                                               const float* __restrict__ fcWc,
                                               const float* __restrict__ fcbc,
                                               void* __restrict__ out,
                                               const int* __restrict__ flags) {
    __shared__ float sm[256];
    int f = threadIdx.x;
    float s = 0.f;
    for (int b = 0; b < G2; ++b) s += partial[b * 128 + f];
    float gm = s * (1.0f / (float)N_NODES);
    sm[f] = gm * fcWc[f];
    sm[128 + f] = gm * fcWc[128 + f];
    __syncthreads();
    for (int off = 64; off >= 1; off >>= 1) {
        if (f < off) {
            sm[f] += sm[f + off];
            sm[128 + f] += sm[128 + f + off];
        }
        __syncthreads();
    }
    if (f == 0) {
        float o0 = sm[0] + fcbc[0];
        float o1 = sm[128] + fcbc[1];
        if (flags[0]) {
            u16* ob = (u16*)out;
            ob[0] = f2bf(o0);
            ob[1] = f2bf(o1);
        } else {
            float* of = (float*)out;
            of[0] = o0;
            of[1] = o1;
        }
    }
}

// ---------- workspace layout (bytes) ----------
// ebuf aliases AGG: ebuf's last read (k_scatter2) precedes agg's first write
// (k_gatherT<1>) in stream order.
#define OFF_FLAGS   0u
#define OFF_DINV    512u        // float[N]
#define OFF_ROWPTR  400896u     // int[N+1]
#define OFF_BCNT    801280u     // u32[NB]
#define OFF_BBASE   802944u     // u32[NB+1]
#define OFF_BCUR    804608u     // u32[NB]
#define OFF_CSR     1201664u    // int[E]
#define OFF_H1      14001664u   // bf16[N*64]
#define OFF_A1      26801664u   // bf16[N*64]
#define OFF_AGG     39601664u   // float[N*64] (25.6MB) / ebuf u32[E] (12.8MB)
#define OFF_PART    65201664u   // float[G2*128]
#define OFF_W1C     65728000u   // u16[256*64]
#define OFF_W2C     65760768u   // u16[64*128]
#define OFF_B1C     65777152u   // float[64]
#define OFF_B2C     65777408u   // float[128]
#define OFF_FCWC    65777920u   // float[256]
#define OFF_FCBC    65778944u   // float[2]

extern "C" void kernel_launch(void* const* d_in, const int* in_sizes, int n_in,
                              void* d_out, int out_size, void* d_ws, size_t ws_size,
                              hipStream_t stream) {
    (void)in_sizes; (void)n_in; (void)out_size; (void)ws_size;
    const void* x   = d_in[0];
    const int*  ei  = (const int*)d_in[1];
    const void* W1  = d_in[2];
    const void* b1  = d_in[3];
    const void* W2  = d_in[4];
    const void* b2  = d_in[5];
    const void* fcW = d_in[6];
    const void* fcb = d_in[7];

    char* ws = (char*)d_ws;
    int*   flags  = (int*)(ws + OFF_FLAGS);
    float* dinv   = (float*)(ws + OFF_DINV);
    int*   rowptr = (int*)(ws + OFF_ROWPTR);
    u32*   bcnt   = (u32*)(ws + OFF_BCNT);
    u32*   bbase  = (u32*)(ws + OFF_BBASE);
    u32*   bcur   = (u32*)(ws + OFF_BCUR);
    int*   csr    = (int*)(ws + OFF_CSR);
    u16*   h1     = (u16*)(ws + OFF_H1);
    u16*   a1     = (u16*)(ws + OFF_A1);
    float* agg    = (float*)(ws + OFF_AGG);
    u32*   ebuf   = (u32*)(ws + OFF_AGG);
    float* partial= (float*)(ws + OFF_PART);
    u16*   W1c    = (u16*)(ws + OFF_W1C);
    u16*   W2c    = (u16*)(ws + OFF_W2C);
    float* b1c    = (float*)(ws + OFF_B1C);
    float* b2c    = (float*)(ws + OFF_B2C);
    float* fcWc   = (float*)(ws + OFF_FCWC);
    float* fcbc   = (float*)(ws + OFF_FCBC);

    k_detect<<<1, 256, 0, stream>>>(x, ei, W1, b1, W2, b2, fcW, fcb,
                                    flags, W1c, W2c, b1c, b2c, fcWc, fcbc, bcnt);
    k_hist1<<<NB, 256, 0, stream>>>(ei, flags, bcnt);
    k_bscan<<<1, 512, 0, stream>>>(bcnt, bbase, bcur, rowptr);
    k_scatter1<<<NB, 512, 0, stream>>>(ei, flags, bcur, ebuf);
    k_scatter2<<<NB, 256, 0, stream>>>(bbase, ebuf, rowptr, dinv, csr);
    k_gemm1<<<N_NODES / 16, 256, 0, stream>>>(x, W1c, h1, flags);
    k_gatherT<0><<<N_NODES / 4, 256, 0, stream>>>(rowptr, csr, dinv, h1, b1c, (void*)a1);
    k_gatherT<1><<<N_NODES / 4, 256, 0, stream>>>(rowptr, csr, dinv, a1, (const float*)nullptr, (void*)agg);
    k_fused2<<<G2, 256, 0, stream>>>(agg, W2c, b2c, partial);
    k_final<<<1, 128, 0, stream>>>(partial, fcWc, fcbc, (void*)d_out, flags);
}

// Round 5
// 495.150 us; speedup vs baseline: 2.7450x; 1.1744x over previous
//
#include <hip/hip_runtime.h>

#define N_NODES 100000
#define N_EDGES 3200000
#define C_IN 256
#define C_H 64
#define C_OUT 128
#define NB 391       // ceil(N_NODES/256) buckets of 256 nodes
#define G2 1024      // blocks for fused gemm2+pool
#define NTILES 6250  // N_NODES/16
#define CH1 8192     // edges per block in hist/scatter1

typedef unsigned int u32;
typedef unsigned short u16;
typedef unsigned long long u64;
typedef __attribute__((ext_vector_type(8))) short bf16x8;
typedef __attribute__((ext_vector_type(4))) float f32x4;

// ---------- bf16 helpers ----------
__device__ __forceinline__ float bflo(u32 p) {
    union { u32 i; float f; } v; v.i = p << 16; return v.f;
}
__device__ __forceinline__ float bfhi(u32 p) {
    union { u32 i; float f; } v; v.i = p & 0xffff0000u; return v.f;
}
__device__ __forceinline__ float bf2f(u16 u) {
    union { u32 i; float f; } v; v.i = ((u32)u) << 16; return v.f;
}
__device__ __forceinline__ u16 f2bf(float f) {
    union { float f; u32 i; } v; v.f = f;
    u32 x = v.i;
    return (u16)((x + 0x7fffu + ((x >> 16) & 1u)) >> 16);  // RNE
}

// ---------- detection + canonicalization ----------
// flags[0]=1 if floats are bf16; flags[1]=1 if edge_index is int64.
// W1 is written in MFMA B-frag order: W1m[((k0*4+nt)*64+lane)*8+j] =
//   W1[(k0*32 + ((lane>>4)&3)*8 + j)*64 + nt*16 + (lane&15)]
__global__ void k_detect(const void* __restrict__ x, const void* __restrict__ ei,
                         const void* __restrict__ W1, const void* __restrict__ b1,
                         const void* __restrict__ W2, const void* __restrict__ b2,
                         const void* __restrict__ fcW, const void* __restrict__ fcb,
                         int* __restrict__ flags,
                         u16* __restrict__ W1m, u16* __restrict__ W2c,
                         float* __restrict__ b1c, float* __restrict__ b2c,
                         float* __restrict__ fcWc, float* __restrict__ fcbc,
                         u32* __restrict__ bucket_cnt) {
    __shared__ int sf[2];
    int t = threadIdx.x;
    if (t < 64) {
        u32 w = ((const u32*)x)[t];
        u32 low = w & 0xffffu;
        int e = (int)((low >> 7) & 0xff);
        bool inw = (e > 96 && e < 160) || (low == 0);
        u64 m = __ballot(inw);
        if (t == 0) sf[0] = (__popcll(m) >= 60) ? 1 : 0;
    } else if (t < 128) {
        int i = t - 64;
        u32 w = ((const u32*)ei)[2 * i + 1];
        u64 m = __ballot(w == 0);
        if (i == 0) sf[1] = (m == ~0ull) ? 1 : 0;
    }
    __syncthreads();
    if (t == 0) { flags[0] = sf[0]; flags[1] = sf[1]; }
    for (int i = t; i < NB; i += 256) bucket_cnt[i] = 0;
    int isbf = sf[0];
    const u16* w1b = (const u16*)W1;  const float* w1f = (const float*)W1;
    for (int i = t; i < C_IN * C_H; i += 256) {
        int j = i & 7, lane = (i >> 3) & 63, nt = (i >> 9) & 3, k0 = i >> 11;
        int k = k0 * 32 + ((lane >> 4) & 3) * 8 + j;
        int n = nt * 16 + (lane & 15);
        W1m[i] = isbf ? w1b[k * C_H + n] : f2bf(w1f[k * C_H + n]);
    }
    if (isbf) {
        const u16* w2 = (const u16*)W2;
        for (int i = t; i < C_H * C_OUT; i += 256) W2c[i] = w2[i];
        const u16* p1 = (const u16*)b1;  const u16* p2 = (const u16*)b2;
        const u16* pw = (const u16*)fcW; const u16* pb = (const u16*)fcb;
        for (int i = t; i < C_H; i += 256) b1c[i] = bf2f(p1[i]);
        for (int i = t; i < C_OUT; i += 256) b2c[i] = bf2f(p2[i]);
        for (int i = t; i < 2 * C_OUT; i += 256) fcWc[i] = bf2f(pw[i]);
        for (int i = t; i < 2; i += 256) fcbc[i] = bf2f(pb[i]);
    } else {
        const float* w2 = (const float*)W2;
        for (int i = t; i < C_H * C_OUT; i += 256) W2c[i] = f2bf(w2[i]);
        const float* p1 = (const float*)b1;  const float* p2 = (const float*)b2;
        const float* pw = (const float*)fcW; const float* pb = (const float*)fcb;
        for (int i = t; i < C_H; i += 256) b1c[i] = p1[i];
        for (int i = t; i < C_OUT; i += 256) b2c[i] = p2[i];
        for (int i = t; i < 2 * C_OUT; i += 256) fcWc[i] = pw[i];
        for (int i = t; i < 2; i += 256) fcbc[i] = pb[i];
    }
}

// ---------- bucket histogram over dst>>8 ----------
__global__ __launch_bounds__(256) void k_hist1(const int* __restrict__ ei,
                                               const int* __restrict__ flags,
                                               u32* __restrict__ bucket_cnt) {
    __shared__ u32 h[NB];
    int t = threadIdx.x;
    int is64 = flags[1];
    for (int i = t; i < NB; i += 256) h[i] = 0;
    __syncthreads();
    int e0 = blockIdx.x * CH1;
    int nv = min(CH1, N_EDGES - e0);
    for (int i = t; i < nv; i += 256) {
        int e = e0 + i;
        int d = is64 ? ei[2 * (N_EDGES + e)] : ei[N_EDGES + e];
        atomicAdd(&h[d >> 8], 1u);
    }
    __syncthreads();
    for (int i = t; i < NB; i += 256)
        if (h[i]) atomicAdd(&bucket_cnt[i], h[i]);
}

// ---------- scan bucket counts -> base + cursor ----------
__global__ __launch_bounds__(512) void k_bscan(const u32* __restrict__ bucket_cnt,
                                               u32* __restrict__ bucket_base,
                                               u32* __restrict__ bucket_cursor,
                                               int* __restrict__ rowptr) {
    __shared__ u32 sm[512];
    int t = threadIdx.x;
    u32 v = (t < NB) ? bucket_cnt[t] : 0;
    sm[t] = v;
    __syncthreads();
    for (int off = 1; off < 512; off <<= 1) {
        u32 a = (t >= off) ? sm[t - off] : 0;
        __syncthreads();
        sm[t] += a;
        __syncthreads();
    }
    if (t < NB) {
        u32 excl = sm[t] - v;
        bucket_base[t] = excl;
        bucket_cursor[t] = excl;
    }
    if (t == 0) {
        bucket_base[NB] = N_EDGES;
        rowptr[N_NODES] = N_EDGES;
    }
}

// ---------- pass 1: bucket-sorted staged scatter (line-dense writes) ----------
__global__ __launch_bounds__(512) void k_scatter1(const int* __restrict__ ei,
                                                  const int* __restrict__ flags,
                                                  u32* __restrict__ bucket_cursor,
                                                  u32* __restrict__ ebuf) {
    __shared__ u32 cnt[NB];
    __shared__ u32 lcur[NB];
    __shared__ u32 gbase[NB];
    __shared__ u32 lofs[512];
    __shared__ u32 stp[CH1];
    __shared__ u16 stb[CH1];
    int t = threadIdx.x;
    int is64 = flags[1];
    int e0 = blockIdx.x * CH1;
    int nv = min(CH1, N_EDGES - e0);
    for (int i = t; i < NB; i += 512) { cnt[i] = 0; lcur[i] = 0; }
    __syncthreads();
    for (int i = t; i < nv; i += 512) {
        int e = e0 + i;
        int d = is64 ? ei[2 * (N_EDGES + e)] : ei[N_EDGES + e];
        atomicAdd(&cnt[d >> 8], 1u);
    }
    __syncthreads();
    u32 v = (t < NB) ? cnt[t] : 0;
    lofs[t] = v;
    __syncthreads();
    for (int off = 1; off < 512; off <<= 1) {
        u32 a = (t >= off) ? lofs[t - off] : 0;
        __syncthreads();
        lofs[t] += a;
        __syncthreads();
    }
    u32 excl = lofs[t] - v;
    __syncthreads();
    lofs[t] = excl;
    __syncthreads();
    for (int i = t; i < nv; i += 512) {
        int e = e0 + i;
        int d, s;
        if (is64) { d = ei[2 * (N_EDGES + e)]; s = ei[2 * e]; }
        else      { d = ei[N_EDGES + e];       s = ei[e]; }
        int b = d >> 8;
        u32 slot = lofs[b] + atomicAdd(&lcur[b], 1u);
        stp[slot] = ((u32)(d & 255) << 20) | (u32)s;
        stb[slot] = (u16)b;
    }
    __syncthreads();
    for (int b = t; b < NB; b += 512) {
        u32 c = cnt[b];
        gbase[b] = c ? atomicAdd(&bucket_cursor[b], c) : 0;
    }
    __syncthreads();
    for (int s = t; s < nv; s += 512) {
        int b = stb[s];
        ebuf[gbase[b] + (s - lofs[b])] = stp[s];
    }
}

// ---------- pass 2: per-bucket local sort -> csr + rowptr + dinv ----------
__global__ __launch_bounds__(256) void k_scatter2(const u32* __restrict__ bucket_base,
                                                  const u32* __restrict__ ebuf,
                                                  int* __restrict__ rowptr,
                                                  float* __restrict__ dinv,
                                                  int* __restrict__ csr) {
    __shared__ int cnt[256];
    __shared__ int pfx[256];
    __shared__ int lcur[256];
    int b = blockIdx.x, t = threadIdx.x;
    int ebeg = (int)bucket_base[b], eend = (int)bucket_base[b + 1];
    cnt[t] = 0;
    lcur[t] = 0;
    __syncthreads();
    for (int i = ebeg + t; i < eend; i += 256)
        atomicAdd(&cnt[(ebuf[i] >> 20) & 255], 1);
    __syncthreads();
    int v = cnt[t];
    pfx[t] = v;
    __syncthreads();
    for (int off = 1; off < 256; off <<= 1) {
        int a = (t >= off) ? pfx[t - off] : 0;
        __syncthreads();
        pfx[t] += a;
        __syncthreads();
    }
    int node = (b << 8) + t;
    if (node < N_NODES) {
        rowptr[node] = ebeg + (pfx[t] - v);
        dinv[node] = rsqrtf((float)(v + 1));
    }
    __syncthreads();
    for (int i = ebeg + t; i < eend; i += 256) {
        u32 p = ebuf[i];
        int dl = (p >> 20) & 255;
        int pos = ebeg + (pfx[dl] - cnt[dl]) + atomicAdd(&lcur[dl], 1);
        csr[pos] = (int)(p & 0x1FFFFu);
    }
}

// ---------- MFMA GEMM1: h1[N,64] = x[N,256] @ W1[256,64] ----------
// Block: 4 waves x 32 nodes = 128 nodes. Per wave: 2 M-tiles, 4 N-tiles,
// 8 K-steps of mfma_f32_16x16x32_bf16. A-frags direct from global; B-frags
// from LDS (frag-ordered W1m, lane-contiguous ds_read_b128).
__global__ __launch_bounds__(256) void k_gemm1(const void* __restrict__ xv,
                                               const u16* __restrict__ W1m,
                                               u16* __restrict__ h1,
                                               const int* __restrict__ flags) {
    __shared__ u16 wlds[C_IN * C_H];   // 32 KB
    int t = threadIdx.x;
    int isbf = flags[0];
    {
        const uint4* src = (const uint4*)W1m;
        uint4* dst = (uint4*)wlds;
#pragma unroll
        for (int it = 0; it < 8; ++it) dst[t + it * 256] = src[t + it * 256];
    }
    __syncthreads();
    int w = t >> 6, lane = t & 63;
    int quad = lane >> 4, mrow = lane & 15;
    int m0 = blockIdx.x * 128 + w * 32;
    if (m0 >= N_NODES) return;

    bf16x8 a[2][8];
    if (isbf) {
        const u16* xb = (const u16*)xv;
#pragma unroll
        for (int mt = 0; mt < 2; ++mt)
#pragma unroll
            for (int k0 = 0; k0 < 8; ++k0)
                a[mt][k0] = *(const bf16x8*)(xb + (size_t)(m0 + mt * 16 + mrow) * C_IN + k0 * 32 + quad * 8);
    } else {
        const float* xf = (const float*)xv;
#pragma unroll
        for (int mt = 0; mt < 2; ++mt)
#pragma unroll
            for (int k0 = 0; k0 < 8; ++k0) {
                const float* p = xf + (size_t)(m0 + mt * 16 + mrow) * C_IN + k0 * 32 + quad * 8;
                float4 v0 = *(const float4*)p;
                float4 v1 = *(const float4*)(p + 4);
                bf16x8 r;
                r[0] = (short)f2bf(v0.x); r[1] = (short)f2bf(v0.y);
                r[2] = (short)f2bf(v0.z); r[3] = (short)f2bf(v0.w);
                r[4] = (short)f2bf(v1.x); r[5] = (short)f2bf(v1.y);
                r[6] = (short)f2bf(v1.z); r[7] = (short)f2bf(v1.w);
                a[mt][k0] = r;
            }
    }

#pragma unroll
    for (int nt = 0; nt < 4; ++nt) {
        bf16x8 b[8];
#pragma unroll
        for (int k0 = 0; k0 < 8; ++k0)
            b[k0] = *(const bf16x8*)&wlds[((k0 * 4 + nt) * 64 + lane) * 8];
        f32x4 acc0 = {0.f, 0.f, 0.f, 0.f};
        f32x4 acc1 = {0.f, 0.f, 0.f, 0.f};
#pragma unroll
        for (int k0 = 0; k0 < 8; ++k0) {
            acc0 = __builtin_amdgcn_mfma_f32_16x16x32_bf16(a[0][k0], b[k0], acc0, 0, 0, 0);
            acc1 = __builtin_amdgcn_mfma_f32_16x16x32_bf16(a[1][k0], b[k0], acc1, 0, 0, 0);
        }
        int ch = nt * 16 + mrow;   // D: col = lane&15
#pragma unroll
        for (int r = 0; r < 4; ++r) {   // D: row = quad*4 + r
            h1[(size_t)(m0 + quad * 4 + r) * C_H + ch] = f2bf(acc0[r]);
            h1[(size_t)(m0 + 16 + quad * 4 + r) * C_H + ch] = f2bf(acc1[r]);
        }
    }
}

// ---------- unified gather over a 64-channel bf16 table ----------
// 8 independent 128B row-loads in flight per wave (2 halves x unroll 4).
template <int MODE>
__global__ __launch_bounds__(256) void k_gatherT(const int* __restrict__ rowptr,
                                                 const int* __restrict__ csr_src,
                                                 const float* __restrict__ dinv,
                                                 const u16* __restrict__ h,
                                                 const float* __restrict__ bias,
                                                 void* __restrict__ outv) {
    int w = threadIdx.x >> 6, lane = threadIdx.x & 63;
    int n = blockIdx.x * 4 + w;
    if (n >= N_NODES) return;
    int j = lane & 31;
    int half = lane >> 5;
    int beg = rowptr[n], end = rowptr[n + 1];
    float sA = 0.f, sB = 0.f;
    int e = beg + half;
    for (; e + 6 < end; e += 8) {
        int s0 = csr_src[e];
        int s1 = csr_src[e + 2];
        int s2 = csr_src[e + 4];
        int s3 = csr_src[e + 6];
        float c0 = dinv[s0], c1 = dinv[s1], c2 = dinv[s2], c3 = dinv[s3];
        u32 p0 = *(const u32*)(h + s0 * C_H + 2 * j);
        u32 p1 = *(const u32*)(h + s1 * C_H + 2 * j);
        u32 p2 = *(const u32*)(h + s2 * C_H + 2 * j);
        u32 p3 = *(const u32*)(h + s3 * C_H + 2 * j);
        sA = fmaf(c0, bflo(p0), sA); sB = fmaf(c0, bfhi(p0), sB);
        sA = fmaf(c1, bflo(p1), sA); sB = fmaf(c1, bfhi(p1), sB);
        sA = fmaf(c2, bflo(p2), sA); sB = fmaf(c2, bfhi(p2), sB);
        sA = fmaf(c3, bflo(p3), sA); sB = fmaf(c3, bfhi(p3), sB);
    }
    for (; e < end; e += 2) {
        int s0 = csr_src[e];
        float c0 = dinv[s0];
        u32 p0 = *(const u32*)(h + s0 * C_H + 2 * j);
        sA = fmaf(c0, bflo(p0), sA);
        sB = fmaf(c0, bfhi(p0), sB);
    }
    sA += __shfl_xor(sA, 32, 64);
    sB += __shfl_xor(sB, 32, 64);

    float dn = dinv[n];
    u32 hn = *(const u32*)(h + n * C_H + 2 * j);
    float oA = dn * sA + dn * dn * bflo(hn);
    float oB = dn * sB + dn * dn * bfhi(hn);
    if (MODE == 0) {
        oA = fmaxf(oA + bias[2 * j], 0.f);
        oB = fmaxf(oB + bias[2 * j + 1], 0.f);
        if (half == 0) {
            u32 pk = (u32)f2bf(oA) | ((u32)f2bf(oB) << 16);
            ((u32*)outv)[n * 32 + j] = pk;
        }
    } else {
        if (half == 0) {
            ((float2*)outv)[n * 32 + j] = make_float2(oA, oB);
        }
    }
}

// ---------- fused GEMM2 + bias + relu + mean-pool partials ----------
__global__ __launch_bounds__(256) void k_fused2(const float* __restrict__ agg,
                                                const u16* __restrict__ W2c,
                                                const float* __restrict__ b2c,
                                                float* __restrict__ partial) {
    __shared__ float wlds[C_H * C_OUT];
    __shared__ float alds[16 * 65];
    __shared__ float psum[256 * 4];
    int t = threadIdx.x;

    const u32* w32 = (const u32*)W2c;
#pragma unroll
    for (int it = 0; it < 16; ++it) {
        int d = t + it * 256;
        u32 pk = w32[d];
        int e0 = d * 2;
        wlds[e0] = bflo(pk);
        wlds[e0 + 1] = bfhi(pk);
    }
    int jt = t & 31, g = t >> 5;
    float bias0 = b2c[jt * 4 + 0], bias1 = b2c[jt * 4 + 1];
    float bias2 = b2c[jt * 4 + 2], bias3 = b2c[jt * 4 + 3];
    float pacc[4] = {0.f, 0.f, 0.f, 0.f};

    for (int tile = blockIdx.x; tile < NTILES; tile += G2) {
        __syncthreads();
        {
            const float* src = agg + (size_t)tile * 16 * C_H;
            int d = t * 4;
            float4 v = *(const float4*)(src + d);
            int r = d >> 6, c = d & 63;
            float* dst = &alds[r * 65 + c];
            dst[0] = v.x; dst[1] = v.y; dst[2] = v.z; dst[3] = v.w;
        }
        __syncthreads();
        float acc[2][4] = {{0.f, 0.f, 0.f, 0.f}, {0.f, 0.f, 0.f, 0.f}};
#pragma unroll 4
        for (int k = 0; k < C_H; ++k) {
            float4 wv = *(const float4*)&wlds[k * C_OUT + jt * 4];
            float av0 = alds[g * 65 + k];
            float av1 = alds[(g + 8) * 65 + k];
            acc[0][0] = fmaf(av0, wv.x, acc[0][0]);
            acc[0][1] = fmaf(av0, wv.y, acc[0][1]);
            acc[0][2] = fmaf(av0, wv.z, acc[0][2]);
            acc[0][3] = fmaf(av0, wv.w, acc[0][3]);
            acc[1][0] = fmaf(av1, wv.x, acc[1][0]);
            acc[1][1] = fmaf(av1, wv.y, acc[1][1]);
            acc[1][2] = fmaf(av1, wv.z, acc[1][2]);
            acc[1][3] = fmaf(av1, wv.w, acc[1][3]);
        }
#pragma unroll
        for (int q = 0; q < 2; ++q) {
            pacc[0] += fmaxf(acc[q][0] + bias0, 0.f);
            pacc[1] += fmaxf(acc[q][1] + bias1, 0.f);
            pacc[2] += fmaxf(acc[q][2] + bias2, 0.f);
            pacc[3] += fmaxf(acc[q][3] + bias3, 0.f);
        }
    }
    psum[t * 4 + 0] = pacc[0];
    psum[t * 4 + 1] = pacc[1];
    psum[t * 4 + 2] = pacc[2];
    psum[t * 4 + 3] = pacc[3];
    __syncthreads();
    if (t < 32) {
#pragma unroll
        for (int i = 0; i < 4; ++i) {
            float s = 0.f;
#pragma unroll
            for (int gg = 0; gg < 8; ++gg) s += psum[(gg * 32 + t) * 4 + i];
            partial[blockIdx.x * C_OUT + t * 4 + i] = s;
        }
    }
}

// ---------- final: mean + FC -> 2 outputs (dtype per flag) ----------
__global__ __launch_bounds__(128) void k_final(const float* __restrict__ partial,
                                               const float* __restrict__ fcWc,
                                               const float* __restrict__ fcbc,
                                               void* __restrict__ out,
                                               const int* __restrict__ flags) {
    __shared__ float sm[256];
    int f = threadIdx.x;
    float s = 0.f;
    for (int b = 0; b < G2; ++b) s += partial[b * 128 + f];
    float gm = s * (1.0f / (float)N_NODES);
    sm[f] = gm * fcWc[f];
    sm[128 + f] = gm * fcWc[128 + f];
    __syncthreads();
    for (int off = 64; off >= 1; off >>= 1) {
        if (f < off) {
            sm[f] += sm[f + off];
            sm[128 + f] += sm[128 + f + off];
        }
        __syncthreads();
    }
    if (f == 0) {
        float o0 = sm[0] + fcbc[0];
        float o1 = sm[128] + fcbc[1];
        if (flags[0]) {
            u16* ob = (u16*)out;
            ob[0] = f2bf(o0);
            ob[1] = f2bf(o1);
        } else {
            float* of = (float*)out;
            of[0] = o0;
            of[1] = o1;
        }
    }
}

// ---------- workspace layout (bytes) ----------
// ebuf aliases AGG: ebuf's last read (k_scatter2) precedes agg's first write
// (k_gatherT<1>) in stream order.
#define OFF_FLAGS   0u
#define OFF_DINV    512u        // float[N]
#define OFF_ROWPTR  400896u     // int[N+1]
#define OFF_BCNT    801280u     // u32[NB]
#define OFF_BBASE   802944u     // u32[NB+1]
#define OFF_BCUR    804608u     // u32[NB]
#define OFF_CSR     1201664u    // int[E]
#define OFF_H1      14001664u   // bf16[N*64]
#define OFF_A1      26801664u   // bf16[N*64]
#define OFF_AGG     39601664u   // float[N*64] (25.6MB) / ebuf u32[E] (12.8MB)
#define OFF_PART    65201664u   // float[G2*128]
#define OFF_W1C     65728000u   // u16[256*64] (MFMA frag order)
#define OFF_W2C     65760768u   // u16[64*128]
#define OFF_B1C     65777152u   // float[64]
#define OFF_B2C     65777408u   // float[128]
#define OFF_FCWC    65777920u   // float[256]
#define OFF_FCBC    65778944u   // float[2]

extern "C" void kernel_launch(void* const* d_in, const int* in_sizes, int n_in,
                              void* d_out, int out_size, void* d_ws, size_t ws_size,
                              hipStream_t stream) {
    (void)in_sizes; (void)n_in; (void)out_size; (void)ws_size;
    const void* x   = d_in[0];
    const int*  ei  = (const int*)d_in[1];
    const void* W1  = d_in[2];
    const void* b1  = d_in[3];
    const void* W2  = d_in[4];
    const void* b2  = d_in[5];
    const void* fcW = d_in[6];
    const void* fcb = d_in[7];

    char* ws = (char*)d_ws;
    int*   flags  = (int*)(ws + OFF_FLAGS);
    float* dinv   = (float*)(ws + OFF_DINV);
    int*   rowptr = (int*)(ws + OFF_ROWPTR);
    u32*   bcnt   = (u32*)(ws + OFF_BCNT);
    u32*   bbase  = (u32*)(ws + OFF_BBASE);
    u32*   bcur   = (u32*)(ws + OFF_BCUR);
    int*   csr    = (int*)(ws + OFF_CSR);
    u16*   h1     = (u16*)(ws + OFF_H1);
    u16*   a1     = (u16*)(ws + OFF_A1);
    float* agg    = (float*)(ws + OFF_AGG);
    u32*   ebuf   = (u32*)(ws + OFF_AGG);
    float* partial= (float*)(ws + OFF_PART);
    u16*   W1m    = (u16*)(ws + OFF_W1C);
    u16*   W2c    = (u16*)(ws + OFF_W2C);
    float* b1c    = (float*)(ws + OFF_B1C);
    float* b2c    = (float*)(ws + OFF_B2C);
    float* fcWc   = (float*)(ws + OFF_FCWC);
    float* fcbc   = (float*)(ws + OFF_FCBC);

    k_detect<<<1, 256, 0, stream>>>(x, ei, W1, b1, W2, b2, fcW, fcb,
                                    flags, W1m, W2c, b1c, b2c, fcWc, fcbc, bcnt);
    k_hist1<<<NB, 256, 0, stream>>>(ei, flags, bcnt);
    k_bscan<<<1, 512, 0, stream>>>(bcnt, bbase, bcur, rowptr);
    k_scatter1<<<NB, 512, 0, stream>>>(ei, flags, bcur, ebuf);
    k_scatter2<<<NB, 256, 0, stream>>>(bbase, ebuf, rowptr, dinv, csr);
    k_gemm1<<<(N_NODES + 127) / 128, 256, 0, stream>>>(x, W1m, h1, flags);
    k_gatherT<0><<<N_NODES / 4, 256, 0, stream>>>(rowptr, csr, dinv, h1, b1c, (void*)a1);
    k_gatherT<1><<<N_NODES / 4, 256, 0, stream>>>(rowptr, csr, dinv, a1, (const float*)nullptr, (void*)agg);
    k_fused2<<<G2, 256, 0, stream>>>(agg, W2c, b2c, partial);
    k_final<<<1, 128, 0, stream>>>(partial, fcWc, fcbc, (void*)d_out, flags);
}

// Round 6
// 476.456 us; speedup vs baseline: 2.8527x; 1.0392x over previous
//
#include <hip/hip_runtime.h>

#define N_NODES 100000
#define N_EDGES 3200000
#define C_IN 256
#define C_H 64
#define C_OUT 128
#define NB 391       // ceil(N_NODES/256) buckets of 256 nodes
#define G2F 625      // blocks for fused gemm2+pool
#define NTILES 6250  // N_NODES/16
#define CH1 8192     // edges per block in hist/scatter1

typedef unsigned int u32;
typedef unsigned short u16;
typedef unsigned long long u64;
typedef __attribute__((ext_vector_type(8))) short bf16x8;
typedef __attribute__((ext_vector_type(4))) float f32x4;

// ---------- bf16 helpers ----------
__device__ __forceinline__ float bflo(u32 p) {
    union { u32 i; float f; } v; v.i = p << 16; return v.f;
}
__device__ __forceinline__ float bfhi(u32 p) {
    union { u32 i; float f; } v; v.i = p & 0xffff0000u; return v.f;
}
__device__ __forceinline__ float bf2f(u16 u) {
    union { u32 i; float f; } v; v.i = ((u32)u) << 16; return v.f;
}
__device__ __forceinline__ u16 f2bf(float f) {
    union { float f; u32 i; } v; v.f = f;
    u32 x = v.i;
    return (u16)((x + 0x7fffu + ((x >> 16) & 1u)) >> 16);  // RNE
}

// ---------- detection + canonicalization ----------
// flags[0]=1 if floats are bf16; flags[1]=1 if edge_index is int64.
// W1m: MFMA B-frag order for GEMM1 (16x16x32, 4 n-tiles, 8 k-steps).
// W2m: MFMA B-frag order for fused2 (8 n-tiles, 2 k-steps).
__global__ void k_detect(const void* __restrict__ x, const void* __restrict__ ei,
                         const void* __restrict__ W1, const void* __restrict__ b1,
                         const void* __restrict__ W2, const void* __restrict__ b2,
                         const void* __restrict__ fcW, const void* __restrict__ fcb,
                         int* __restrict__ flags,
                         u16* __restrict__ W1m, u16* __restrict__ W2m,
                         float* __restrict__ b1c, float* __restrict__ b2c,
                         float* __restrict__ fcWc, float* __restrict__ fcbc,
                         u32* __restrict__ bucket_cnt) {
    __shared__ int sf[2];
    int t = threadIdx.x;
    if (t < 64) {
        u32 w = ((const u32*)x)[t];
        u32 low = w & 0xffffu;
        int e = (int)((low >> 7) & 0xff);
        bool inw = (e > 96 && e < 160) || (low == 0);
        u64 m = __ballot(inw);
        if (t == 0) sf[0] = (__popcll(m) >= 60) ? 1 : 0;
    } else if (t < 128) {
        int i = t - 64;
        u32 w = ((const u32*)ei)[2 * i + 1];
        u64 m = __ballot(w == 0);
        if (i == 0) sf[1] = (m == ~0ull) ? 1 : 0;
    }
    __syncthreads();
    if (t == 0) { flags[0] = sf[0]; flags[1] = sf[1]; }
    for (int i = t; i < NB; i += 256) bucket_cnt[i] = 0;
    int isbf = sf[0];
    const u16* w1b = (const u16*)W1;  const float* w1f = (const float*)W1;
    for (int i = t; i < C_IN * C_H; i += 256) {
        int j = i & 7, lane = (i >> 3) & 63, nt = (i >> 9) & 3, k0 = i >> 11;
        int k = k0 * 32 + ((lane >> 4) & 3) * 8 + j;
        int n = nt * 16 + (lane & 15);
        W1m[i] = isbf ? w1b[k * C_H + n] : f2bf(w1f[k * C_H + n]);
    }
    const u16* w2b = (const u16*)W2;  const float* w2f = (const float*)W2;
    for (int i = t; i < C_H * C_OUT; i += 256) {
        int j = i & 7, lane = (i >> 3) & 63, nt = (i >> 9) & 7, k0 = (i >> 12) & 1;
        int k = k0 * 32 + ((lane >> 4) & 3) * 8 + j;
        int n = nt * 16 + (lane & 15);
        W2m[i] = isbf ? w2b[k * C_OUT + n] : f2bf(w2f[k * C_OUT + n]);
    }
    if (isbf) {
        const u16* p1 = (const u16*)b1;  const u16* p2 = (const u16*)b2;
        const u16* pw = (const u16*)fcW; const u16* pb = (const u16*)fcb;
        for (int i = t; i < C_H; i += 256) b1c[i] = bf2f(p1[i]);
        for (int i = t; i < C_OUT; i += 256) b2c[i] = bf2f(p2[i]);
        for (int i = t; i < 2 * C_OUT; i += 256) fcWc[i] = bf2f(pw[i]);
        for (int i = t; i < 2; i += 256) fcbc[i] = bf2f(pb[i]);
    } else {
        const float* p1 = (const float*)b1;  const float* p2 = (const float*)b2;
        const float* pw = (const float*)fcW; const float* pb = (const float*)fcb;
        for (int i = t; i < C_H; i += 256) b1c[i] = p1[i];
        for (int i = t; i < C_OUT; i += 256) b2c[i] = p2[i];
        for (int i = t; i < 2 * C_OUT; i += 256) fcWc[i] = pw[i];
        for (int i = t; i < 2; i += 256) fcbc[i] = pb[i];
    }
}

// ---------- bucket histogram over dst>>8 ----------
__global__ __launch_bounds__(256) void k_hist1(const int* __restrict__ ei,
                                               const int* __restrict__ flags,
                                               u32* __restrict__ bucket_cnt) {
    __shared__ u32 h[NB];
    int t = threadIdx.x;
    int is64 = flags[1];
    for (int i = t; i < NB; i += 256) h[i] = 0;
    __syncthreads();
    int e0 = blockIdx.x * CH1;
    int nv = min(CH1, N_EDGES - e0);
    for (int i = t; i < nv; i += 256) {
        int e = e0 + i;
        int d = is64 ? ei[2 * (N_EDGES + e)] : ei[N_EDGES + e];
        atomicAdd(&h[d >> 8], 1u);
    }
    __syncthreads();
    for (int i = t; i < NB; i += 256)
        if (h[i]) atomicAdd(&bucket_cnt[i], h[i]);
}

// ---------- scan bucket counts -> base + cursor ----------
__global__ __launch_bounds__(512) void k_bscan(const u32* __restrict__ bucket_cnt,
                                               u32* __restrict__ bucket_base,
                                               u32* __restrict__ bucket_cursor,
                                               int* __restrict__ rowptr) {
    __shared__ u32 sm[512];
    int t = threadIdx.x;
    u32 v = (t < NB) ? bucket_cnt[t] : 0;
    sm[t] = v;
    __syncthreads();
    for (int off = 1; off < 512; off <<= 1) {
        u32 a = (t >= off) ? sm[t - off] : 0;
        __syncthreads();
        sm[t] += a;
        __syncthreads();
    }
    if (t < NB) {
        u32 excl = sm[t] - v;
        bucket_base[t] = excl;
        bucket_cursor[t] = excl;
    }
    if (t == 0) {
        bucket_base[NB] = N_EDGES;
        rowptr[N_NODES] = N_EDGES;
    }
}

// ---------- pass 1: bucket-sorted staged scatter (line-dense writes) ----------
__global__ __launch_bounds__(512) void k_scatter1(const int* __restrict__ ei,
                                                  const int* __restrict__ flags,
                                                  u32* __restrict__ bucket_cursor,
                                                  u32* __restrict__ ebuf) {
    __shared__ u32 cnt[NB];
    __shared__ u32 lcur[NB];
    __shared__ u32 gbase[NB];
    __shared__ u32 lofs[512];
    __shared__ u32 stp[CH1];
    __shared__ u16 stb[CH1];
    int t = threadIdx.x;
    int is64 = flags[1];
    int e0 = blockIdx.x * CH1;
    int nv = min(CH1, N_EDGES - e0);
    for (int i = t; i < NB; i += 512) { cnt[i] = 0; lcur[i] = 0; }
    __syncthreads();
    for (int i = t; i < nv; i += 512) {
        int e = e0 + i;
        int d = is64 ? ei[2 * (N_EDGES + e)] : ei[N_EDGES + e];
        atomicAdd(&cnt[d >> 8], 1u);
    }
    __syncthreads();
    u32 v = (t < NB) ? cnt[t] : 0;
    lofs[t] = v;
    __syncthreads();
    for (int off = 1; off < 512; off <<= 1) {
        u32 a = (t >= off) ? lofs[t - off] : 0;
        __syncthreads();
        lofs[t] += a;
        __syncthreads();
    }
    u32 excl = lofs[t] - v;
    __syncthreads();
    lofs[t] = excl;
    __syncthreads();
    for (int i = t; i < nv; i += 512) {
        int e = e0 + i;
        int d, s;
        if (is64) { d = ei[2 * (N_EDGES + e)]; s = ei[2 * e]; }
        else      { d = ei[N_EDGES + e];       s = ei[e]; }
        int b = d >> 8;
        u32 slot = lofs[b] + atomicAdd(&lcur[b], 1u);
        stp[slot] = ((u32)(d & 255) << 20) | (u32)s;
        stb[slot] = (u16)b;
    }
    __syncthreads();
    for (int b = t; b < NB; b += 512) {
        u32 c = cnt[b];
        gbase[b] = c ? atomicAdd(&bucket_cursor[b], c) : 0;
    }
    __syncthreads();
    for (int s = t; s < nv; s += 512) {
        int b = stb[s];
        ebuf[gbase[b] + (s - lofs[b])] = stp[s];
    }
}

// ---------- pass 2: per-bucket local sort -> csr + rowptr + dinv ----------
__global__ __launch_bounds__(256) void k_scatter2(const u32* __restrict__ bucket_base,
                                                  const u32* __restrict__ ebuf,
                                                  int* __restrict__ rowptr,
                                                  float* __restrict__ dinv,
                                                  int* __restrict__ csr) {
    __shared__ int cnt[256];
    __shared__ int pfx[256];
    __shared__ int lcur[256];
    int b = blockIdx.x, t = threadIdx.x;
    int ebeg = (int)bucket_base[b], eend = (int)bucket_base[b + 1];
    cnt[t] = 0;
    lcur[t] = 0;
    __syncthreads();
    for (int i = ebeg + t; i < eend; i += 256)
        atomicAdd(&cnt[(ebuf[i] >> 20) & 255], 1);
    __syncthreads();
    int v = cnt[t];
    pfx[t] = v;
    __syncthreads();
    for (int off = 1; off < 256; off <<= 1) {
        int a = (t >= off) ? pfx[t - off] : 0;
        __syncthreads();
        pfx[t] += a;
        __syncthreads();
    }
    int node = (b << 8) + t;
    if (node < N_NODES) {
        rowptr[node] = ebeg + (pfx[t] - v);
        dinv[node] = rsqrtf((float)(v + 1));
    }
    __syncthreads();
    for (int i = ebeg + t; i < eend; i += 256) {
        u32 p = ebuf[i];
        int dl = (p >> 20) & 255;
        int pos = ebeg + (pfx[dl] - cnt[dl]) + atomicAdd(&lcur[dl], 1);
        csr[pos] = (int)(p & 0x1FFFFu);
    }
}

// ---------- MFMA GEMM1: h1[N,64] = x[N,256] @ W1[256,64] ----------
__global__ __launch_bounds__(256) void k_gemm1(const void* __restrict__ xv,
                                               const u16* __restrict__ W1m,
                                               u16* __restrict__ h1,
                                               const int* __restrict__ flags) {
    __shared__ u16 wlds[C_IN * C_H];   // 32 KB
    int t = threadIdx.x;
    int isbf = flags[0];
    {
        const uint4* src = (const uint4*)W1m;
        uint4* dst = (uint4*)wlds;
#pragma unroll
        for (int it = 0; it < 8; ++it) dst[t + it * 256] = src[t + it * 256];
    }
    __syncthreads();
    int w = t >> 6, lane = t & 63;
    int quad = lane >> 4, mrow = lane & 15;
    int m0 = blockIdx.x * 128 + w * 32;
    if (m0 >= N_NODES) return;

    bf16x8 a[2][8];
    if (isbf) {
        const u16* xb = (const u16*)xv;
#pragma unroll
        for (int mt = 0; mt < 2; ++mt)
#pragma unroll
            for (int k0 = 0; k0 < 8; ++k0)
                a[mt][k0] = *(const bf16x8*)(xb + (size_t)(m0 + mt * 16 + mrow) * C_IN + k0 * 32 + quad * 8);
    } else {
        const float* xf = (const float*)xv;
#pragma unroll
        for (int mt = 0; mt < 2; ++mt)
#pragma unroll
            for (int k0 = 0; k0 < 8; ++k0) {
                const float* p = xf + (size_t)(m0 + mt * 16 + mrow) * C_IN + k0 * 32 + quad * 8;
                float4 v0 = *(const float4*)p;
                float4 v1 = *(const float4*)(p + 4);
                bf16x8 r;
                r[0] = (short)f2bf(v0.x); r[1] = (short)f2bf(v0.y);
                r[2] = (short)f2bf(v0.z); r[3] = (short)f2bf(v0.w);
                r[4] = (short)f2bf(v1.x); r[5] = (short)f2bf(v1.y);
                r[6] = (short)f2bf(v1.z); r[7] = (short)f2bf(v1.w);
                a[mt][k0] = r;
            }
    }

#pragma unroll
    for (int nt = 0; nt < 4; ++nt) {
        bf16x8 b[8];
#pragma unroll
        for (int k0 = 0; k0 < 8; ++k0)
            b[k0] = *(const bf16x8*)&wlds[((k0 * 4 + nt) * 64 + lane) * 8];
        f32x4 acc0 = {0.f, 0.f, 0.f, 0.f};
        f32x4 acc1 = {0.f, 0.f, 0.f, 0.f};
#pragma unroll
        for (int k0 = 0; k0 < 8; ++k0) {
            acc0 = __builtin_amdgcn_mfma_f32_16x16x32_bf16(a[0][k0], b[k0], acc0, 0, 0, 0);
            acc1 = __builtin_amdgcn_mfma_f32_16x16x32_bf16(a[1][k0], b[k0], acc1, 0, 0, 0);
        }
        int ch = nt * 16 + mrow;   // D: col = lane&15
#pragma unroll
        for (int r = 0; r < 4; ++r) {   // D: row = quad*4 + r
            h1[(size_t)(m0 + quad * 4 + r) * C_H + ch] = f2bf(acc0[r]);
            h1[(size_t)(m0 + 16 + quad * 4 + r) * C_H + ch] = f2bf(acc1[r]);
        }
    }
}

// ---------- unified gather over a 64-channel bf16 table ----------
// 16 independent 128B row-loads in flight per wave (2 halves x unroll 8).
template <int MODE>
__global__ __launch_bounds__(256) void k_gatherT(const int* __restrict__ rowptr,
                                                 const int* __restrict__ csr_src,
                                                 const float* __restrict__ dinv,
                                                 const u16* __restrict__ h,
                                                 const float* __restrict__ bias,
                                                 void* __restrict__ outv) {
    int w = threadIdx.x >> 6, lane = threadIdx.x & 63;
    int n = blockIdx.x * 4 + w;
    if (n >= N_NODES) return;
    int j = lane & 31;
    int half = lane >> 5;
    int beg = rowptr[n], end = rowptr[n + 1];
    float sA = 0.f, sB = 0.f;
    int e = beg + half;
    for (; e + 14 < end; e += 16) {
        int s[8]; float c[8]; u32 p[8];
#pragma unroll
        for (int q = 0; q < 8; ++q) s[q] = csr_src[e + 2 * q];
#pragma unroll
        for (int q = 0; q < 8; ++q) c[q] = dinv[s[q]];
#pragma unroll
        for (int q = 0; q < 8; ++q) p[q] = *(const u32*)(h + s[q] * C_H + 2 * j);
#pragma unroll
        for (int q = 0; q < 8; ++q) {
            sA = fmaf(c[q], bflo(p[q]), sA);
            sB = fmaf(c[q], bfhi(p[q]), sB);
        }
    }
    for (; e + 6 < end; e += 8) {
        int s[4]; float c[4]; u32 p[4];
#pragma unroll
        for (int q = 0; q < 4; ++q) s[q] = csr_src[e + 2 * q];
#pragma unroll
        for (int q = 0; q < 4; ++q) c[q] = dinv[s[q]];
#pragma unroll
        for (int q = 0; q < 4; ++q) p[q] = *(const u32*)(h + s[q] * C_H + 2 * j);
#pragma unroll
        for (int q = 0; q < 4; ++q) {
            sA = fmaf(c[q], bflo(p[q]), sA);
            sB = fmaf(c[q], bfhi(p[q]), sB);
        }
    }
    for (; e < end; e += 2) {
        int s0 = csr_src[e];
        float c0 = dinv[s0];
        u32 p0 = *(const u32*)(h + s0 * C_H + 2 * j);
        sA = fmaf(c0, bflo(p0), sA);
        sB = fmaf(c0, bfhi(p0), sB);
    }
    sA += __shfl_xor(sA, 32, 64);
    sB += __shfl_xor(sB, 32, 64);

    float dn = dinv[n];
    u32 hn = *(const u32*)(h + n * C_H + 2 * j);
    float oA = dn * sA + dn * dn * bflo(hn);
    float oB = dn * sB + dn * dn * bfhi(hn);
    if (MODE == 0) {
        oA = fmaxf(oA + bias[2 * j], 0.f);
        oB = fmaxf(oB + bias[2 * j + 1], 0.f);
        if (half == 0) {
            u32 pk = (u32)f2bf(oA) | ((u32)f2bf(oB) << 16);
            ((u32*)outv)[n * 32 + j] = pk;
        }
    } else {
        if (half == 0) {
            ((float2*)outv)[n * 32 + j] = make_float2(oA, oB);
        }
    }
}

// ---------- fused MFMA GEMM2 + bias + relu + mean-pool partials ----------
// Per 16-node tile: A = agg[16][64] (fp32 -> bf16 in-reg), B = W2m frag-order.
// D layout: col(lane&15) = out-ch within n-tile, row(quad*4+r) = node.
__global__ __launch_bounds__(256) void k_fused2(const float* __restrict__ agg,
                                                const u16* __restrict__ W2m,
                                                const float* __restrict__ b2c,
                                                float* __restrict__ partial) {
    __shared__ float psum[4 * 8 * 64];   // [wave][nt][lane], 8 KB
    int t = threadIdx.x;
    int w = t >> 6, lane = t & 63;
    int quad = lane >> 4, m = lane & 15;

    bf16x8 b[2][8];
#pragma unroll
    for (int k0 = 0; k0 < 2; ++k0)
#pragma unroll
        for (int nt = 0; nt < 8; ++nt)
            b[k0][nt] = *(const bf16x8*)&W2m[((k0 * 8 + nt) * 64 + lane) * 8];

    float pacc[8] = {0.f, 0.f, 0.f, 0.f, 0.f, 0.f, 0.f, 0.f};
    float bias[8];
#pragma unroll
    for (int nt = 0; nt < 8; ++nt) bias[nt] = b2c[nt * 16 + m];

    for (int tile = blockIdx.x * 4 + w; tile < NTILES; tile += G2F * 4) {
        const float* arow = agg + (size_t)(tile * 16 + m) * C_H + quad * 8;
        bf16x8 a[2];
#pragma unroll
        for (int k0 = 0; k0 < 2; ++k0) {
            float4 v0 = *(const float4*)(arow + k0 * 32);
            float4 v1 = *(const float4*)(arow + k0 * 32 + 4);
            bf16x8 r;
            r[0] = (short)f2bf(v0.x); r[1] = (short)f2bf(v0.y);
            r[2] = (short)f2bf(v0.z); r[3] = (short)f2bf(v0.w);
            r[4] = (short)f2bf(v1.x); r[5] = (short)f2bf(v1.y);
            r[6] = (short)f2bf(v1.z); r[7] = (short)f2bf(v1.w);
            a[k0] = r;
        }
#pragma unroll
        for (int nt = 0; nt < 8; ++nt) {
            f32x4 acc = {0.f, 0.f, 0.f, 0.f};
            acc = __builtin_amdgcn_mfma_f32_16x16x32_bf16(a[0], b[0][nt], acc, 0, 0, 0);
            acc = __builtin_amdgcn_mfma_f32_16x16x32_bf16(a[1], b[1][nt], acc, 0, 0, 0);
#pragma unroll
            for (int r = 0; r < 4; ++r)
                pacc[nt] += fmaxf(acc[r] + bias[nt], 0.f);
        }
    }
#pragma unroll
    for (int nt = 0; nt < 8; ++nt) psum[(w * 8 + nt) * 64 + lane] = pacc[nt];
    __syncthreads();
    if (t < 128) {
        int nt = t >> 4, m2 = t & 15;
        float s = 0.f;
#pragma unroll
        for (int ww = 0; ww < 4; ++ww)
#pragma unroll
            for (int q = 0; q < 4; ++q)
                s += psum[(ww * 8 + nt) * 64 + q * 16 + m2];
        partial[blockIdx.x * C_OUT + t] = s;   // ch = nt*16 + m2 = t
    }
}

// ---------- final: mean + FC -> 2 outputs (dtype per flag) ----------
__global__ __launch_bounds__(512) void k_final(const float* __restrict__ partial,
                                               const float* __restrict__ fcWc,
                                               const float* __restrict__ fcbc,
                                               void* __restrict__ out,
                                               const int* __restrict__ flags) {
    __shared__ float sm[512];
    __shared__ float red[256];
    int t = threadIdx.x;
    int f = t & 127, c = t >> 7;
    float s = 0.f;
    for (int b = c; b < G2F; b += 4) s += partial[b * 128 + f];
    sm[t] = s;
    __syncthreads();
    if (t < 128) {
        float gm = (sm[t] + sm[t + 128] + sm[t + 256] + sm[t + 384]) * (1.0f / (float)N_NODES);
        red[t] = gm * fcWc[t];
        red[128 + t] = gm * fcWc[128 + t];
    }
    __syncthreads();
    for (int off = 64; off >= 1; off >>= 1) {
        if (t < off) {
            red[t] += red[t + off];
            red[128 + t] += red[128 + t + off];
        }
        __syncthreads();
    }
    if (t == 0) {
        float o0 = red[0] + fcbc[0];
        float o1 = red[128] + fcbc[1];
        if (flags[0]) {
            u16* ob = (u16*)out;
            ob[0] = f2bf(o0);
            ob[1] = f2bf(o1);
        } else {
            float* of = (float*)out;
            of[0] = o0;
            of[1] = o1;
        }
    }
}

// ---------- workspace layout (bytes) ----------
// ebuf aliases AGG: ebuf's last read (k_scatter2) precedes agg's first write
// (k_gatherT<1>) in stream order.
#define OFF_FLAGS   0u
#define OFF_DINV    512u        // float[N]
#define OFF_ROWPTR  400896u     // int[N+1]
#define OFF_BCNT    801280u     // u32[NB]
#define OFF_BBASE   802944u     // u32[NB+1]
#define OFF_BCUR    804608u     // u32[NB]
#define OFF_CSR     1201664u    // int[E]
#define OFF_H1      14001664u   // bf16[N*64]
#define OFF_A1      26801664u   // bf16[N*64]
#define OFF_AGG     39601664u   // float[N*64] (25.6MB) / ebuf u32[E] (12.8MB)
#define OFF_PART    65201664u   // float[G2F*128]
#define OFF_W1C     65728000u   // u16[256*64] (MFMA frag order)
#define OFF_W2C     65760768u   // u16[64*128] (MFMA frag order)
#define OFF_B1C     65777152u   // float[64]
#define OFF_B2C     65777408u   // float[128]
#define OFF_FCWC    65777920u   // float[256]
#define OFF_FCBC    65778944u   // float[2]

extern "C" void kernel_launch(void* const* d_in, const int* in_sizes, int n_in,
                              void* d_out, int out_size, void* d_ws, size_t ws_size,
                              hipStream_t stream) {
    (void)in_sizes; (void)n_in; (void)out_size; (void)ws_size;
    const void* x   = d_in[0];
    const int*  ei  = (const int*)d_in[1];
    const void* W1  = d_in[2];
    const void* b1  = d_in[3];
    const void* W2  = d_in[4];
    const void* b2  = d_in[5];
    const void* fcW = d_in[6];
    const void* fcb = d_in[7];

    char* ws = (char*)d_ws;
    int*   flags  = (int*)(ws + OFF_FLAGS);
    float* dinv   = (float*)(ws + OFF_DINV);
    int*   rowptr = (int*)(ws + OFF_ROWPTR);
    u32*   bcnt   = (u32*)(ws + OFF_BCNT);
    u32*   bbase  = (u32*)(ws + OFF_BBASE);
    u32*   bcur   = (u32*)(ws + OFF_BCUR);
    int*   csr    = (int*)(ws + OFF_CSR);
    u16*   h1     = (u16*)(ws + OFF_H1);
    u16*   a1     = (u16*)(ws + OFF_A1);
    float* agg    = (float*)(ws + OFF_AGG);
    u32*   ebuf   = (u32*)(ws + OFF_AGG);
    float* partial= (float*)(ws + OFF_PART);
    u16*   W1m    = (u16*)(ws + OFF_W1C);
    u16*   W2m    = (u16*)(ws + OFF_W2C);
    float* b1c    = (float*)(ws + OFF_B1C);
    float* b2c    = (float*)(ws + OFF_B2C);
    float* fcWc   = (float*)(ws + OFF_FCWC);
    float* fcbc   = (float*)(ws + OFF_FCBC);

    k_detect<<<1, 256, 0, stream>>>(x, ei, W1, b1, W2, b2, fcW, fcb,
                                    flags, W1m, W2m, b1c, b2c, fcWc, fcbc, bcnt);
    k_hist1<<<NB, 256, 0, stream>>>(ei, flags, bcnt);
    k_bscan<<<1, 512, 0, stream>>>(bcnt, bbase, bcur, rowptr);
    k_scatter1<<<NB, 512, 0, stream>>>(ei, flags, bcur, ebuf);
    k_scatter2<<<NB, 256, 0, stream>>>(bbase, ebuf, rowptr, dinv, csr);
    k_gemm1<<<(N_NODES + 127) / 128, 256, 0, stream>>>(x, W1m, h1, flags);
    k_gatherT<0><<<N_NODES / 4, 256, 0, stream>>>(rowptr, csr, dinv, h1, b1c, (void*)a1);
    k_gatherT<1><<<N_NODES / 4, 256, 0, stream>>>(rowptr, csr, dinv, a1, (const float*)nullptr, (void*)agg);
    k_fused2<<<G2F, 256, 0, stream>>>(agg, W2m, b2c, partial);
    k_final<<<1, 512, 0, stream>>>(partial, fcWc, fcbc, (void*)d_out, flags);
}

// Round 7
// 419.005 us; speedup vs baseline: 3.2438x; 1.1371x over previous
//
#include <hip/hip_runtime.h>

#define N_NODES 100000
#define N_EDGES 3200000
#define C_IN 256
#define C_H 64
#define C_OUT 128
#define NB 391       // ceil(N_NODES/256) buckets of 256 nodes
#define G2F 625      // blocks for fused gemm2+pool
#define NTILES 6250  // N_NODES/16
#define CH1 8192     // edges per block in hist/scatter1

typedef unsigned int u32;
typedef unsigned short u16;
typedef unsigned long long u64;
typedef __attribute__((ext_vector_type(8))) short bf16x8;
typedef __attribute__((ext_vector_type(4))) float f32x4;

// ---------- bf16 helpers ----------
__device__ __forceinline__ float bflo(u32 p) {
    union { u32 i; float f; } v; v.i = p << 16; return v.f;
}
__device__ __forceinline__ float bfhi(u32 p) {
    union { u32 i; float f; } v; v.i = p & 0xffff0000u; return v.f;
}
__device__ __forceinline__ float bf2f(u16 u) {
    union { u32 i; float f; } v; v.i = ((u32)u) << 16; return v.f;
}
__device__ __forceinline__ u16 f2bf(float f) {
    union { float f; u32 i; } v; v.f = f;
    u32 x = v.i;
    return (u16)((x + 0x7fffu + ((x >> 16) & 1u)) >> 16);  // RNE
}

// ---------- slim detection: flags + small tensors ----------
// flags[0]=1 if floats are bf16; flags[1]=1 if edge_index is int64.
__global__ void k_detect(const void* __restrict__ x, const void* __restrict__ ei,
                         const void* __restrict__ b1, const void* __restrict__ b2,
                         const void* __restrict__ fcW, const void* __restrict__ fcb,
                         int* __restrict__ flags,
                         float* __restrict__ b1c, float* __restrict__ b2c,
                         float* __restrict__ fcWc, float* __restrict__ fcbc) {
    __shared__ int sf[2];
    int t = threadIdx.x;
    if (t < 64) {
        u32 w = ((const u32*)x)[t];
        u32 low = w & 0xffffu;
        int e = (int)((low >> 7) & 0xff);
        bool inw = (e > 96 && e < 160) || (low == 0);
        u64 m = __ballot(inw);
        if (t == 0) sf[0] = (__popcll(m) >= 60) ? 1 : 0;
    } else if (t < 128) {
        int i = t - 64;
        u32 w = ((const u32*)ei)[2 * i + 1];
        u64 m = __ballot(w == 0);
        if (i == 0) sf[1] = (m == ~0ull) ? 1 : 0;
    }
    __syncthreads();
    if (t == 0) { flags[0] = sf[0]; flags[1] = sf[1]; }
    int isbf = sf[0];
    if (isbf) {
        const u16* p1 = (const u16*)b1;  const u16* p2 = (const u16*)b2;
        const u16* pw = (const u16*)fcW; const u16* pb = (const u16*)fcb;
        for (int i = t; i < C_H; i += 256) b1c[i] = bf2f(p1[i]);
        for (int i = t; i < C_OUT; i += 256) b2c[i] = bf2f(p2[i]);
        for (int i = t; i < 2 * C_OUT; i += 256) fcWc[i] = bf2f(pw[i]);
        for (int i = t; i < 2; i += 256) fcbc[i] = bf2f(pb[i]);
    } else {
        const float* p1 = (const float*)b1;  const float* p2 = (const float*)b2;
        const float* pw = (const float*)fcW; const float* pb = (const float*)fcb;
        for (int i = t; i < C_H; i += 256) b1c[i] = p1[i];
        for (int i = t; i < C_OUT; i += 256) b2c[i] = p2[i];
        for (int i = t; i < 2 * C_OUT; i += 256) fcWc[i] = pw[i];
        for (int i = t; i < 2; i += 256) fcbc[i] = pb[i];
    }
}

// ---------- parallel prep: W1m/W2m frag-order swizzles + bucket_cnt zero ----------
// W1m: B-frag order, 4 n-tiles x 8 k-steps. W2m: 8 n-tiles x 2 k-steps.
__global__ __launch_bounds__(256) void k_prep(const void* __restrict__ W1,
                                              const void* __restrict__ W2,
                                              const int* __restrict__ flags,
                                              u16* __restrict__ W1m, u16* __restrict__ W2m,
                                              u32* __restrict__ bucket_cnt) {
    int b = blockIdx.x, t = threadIdx.x;
    int isbf = flags[0];
    int i = b * 256 + t;
    if (i < NB) bucket_cnt[i] = 0;
    if (i < C_IN * C_H) {
        const u16* w1b = (const u16*)W1; const float* w1f = (const float*)W1;
        int j = i & 7, lane = (i >> 3) & 63, nt = (i >> 9) & 3, k0 = i >> 11;
        int k = k0 * 32 + ((lane >> 4) & 3) * 8 + j;
        int n = nt * 16 + (lane & 15);
        W1m[i] = isbf ? w1b[k * C_H + n] : f2bf(w1f[k * C_H + n]);
    } else {
        int i2 = i - C_IN * C_H;
        const u16* w2b = (const u16*)W2; const float* w2f = (const float*)W2;
        int j = i2 & 7, lane = (i2 >> 3) & 63, nt = (i2 >> 9) & 7, k0 = (i2 >> 12) & 1;
        int k = k0 * 32 + ((lane >> 4) & 3) * 8 + j;
        int n = nt * 16 + (lane & 15);
        W2m[i2] = isbf ? w2b[k * C_OUT + n] : f2bf(w2f[k * C_OUT + n]);
    }
}

// ---------- bucket histogram over dst>>8 ----------
__global__ __launch_bounds__(256) void k_hist1(const int* __restrict__ ei,
                                               const int* __restrict__ flags,
                                               u32* __restrict__ bucket_cnt) {
    __shared__ u32 h[NB];
    int t = threadIdx.x;
    int is64 = flags[1];
    for (int i = t; i < NB; i += 256) h[i] = 0;
    __syncthreads();
    int e0 = blockIdx.x * CH1;
    int nv = min(CH1, N_EDGES - e0);
    for (int i = t; i < nv; i += 256) {
        int e = e0 + i;
        int d = is64 ? ei[2 * (N_EDGES + e)] : ei[N_EDGES + e];
        atomicAdd(&h[d >> 8], 1u);
    }
    __syncthreads();
    for (int i = t; i < NB; i += 256)
        if (h[i]) atomicAdd(&bucket_cnt[i], h[i]);
}

// ---------- scan bucket counts -> base + cursor ----------
__global__ __launch_bounds__(512) void k_bscan(const u32* __restrict__ bucket_cnt,
                                               u32* __restrict__ bucket_base,
                                               u32* __restrict__ bucket_cursor,
                                               int* __restrict__ rowptr) {
    __shared__ u32 sm[512];
    int t = threadIdx.x;
    u32 v = (t < NB) ? bucket_cnt[t] : 0;
    sm[t] = v;
    __syncthreads();
    for (int off = 1; off < 512; off <<= 1) {
        u32 a = (t >= off) ? sm[t - off] : 0;
        __syncthreads();
        sm[t] += a;
        __syncthreads();
    }
    if (t < NB) {
        u32 excl = sm[t] - v;
        bucket_base[t] = excl;
        bucket_cursor[t] = excl;
    }
    if (t == 0) {
        bucket_base[NB] = N_EDGES;
        rowptr[N_NODES] = N_EDGES;
    }
}

// ---------- pass 1: bucket-sorted staged scatter (line-dense writes) ----------
__global__ __launch_bounds__(512) void k_scatter1(const int* __restrict__ ei,
                                                  const int* __restrict__ flags,
                                                  u32* __restrict__ bucket_cursor,
                                                  u32* __restrict__ ebuf) {
    __shared__ u32 cnt[NB];
    __shared__ u32 lcur[NB];
    __shared__ u32 gbase[NB];
    __shared__ u32 lofs[512];
    __shared__ u32 stp[CH1];
    __shared__ u16 stb[CH1];
    int t = threadIdx.x;
    int is64 = flags[1];
    int e0 = blockIdx.x * CH1;
    int nv = min(CH1, N_EDGES - e0);
    for (int i = t; i < NB; i += 512) { cnt[i] = 0; lcur[i] = 0; }
    __syncthreads();
    for (int i = t; i < nv; i += 512) {
        int e = e0 + i;
        int d = is64 ? ei[2 * (N_EDGES + e)] : ei[N_EDGES + e];
        atomicAdd(&cnt[d >> 8], 1u);
    }
    __syncthreads();
    u32 v = (t < NB) ? cnt[t] : 0;
    lofs[t] = v;
    __syncthreads();
    for (int off = 1; off < 512; off <<= 1) {
        u32 a = (t >= off) ? lofs[t - off] : 0;
        __syncthreads();
        lofs[t] += a;
        __syncthreads();
    }
    u32 excl = lofs[t] - v;
    __syncthreads();
    lofs[t] = excl;
    __syncthreads();
    for (int i = t; i < nv; i += 512) {
        int e = e0 + i;
        int d, s;
        if (is64) { d = ei[2 * (N_EDGES + e)]; s = ei[2 * e]; }
        else      { d = ei[N_EDGES + e];       s = ei[e]; }
        int b = d >> 8;
        u32 slot = lofs[b] + atomicAdd(&lcur[b], 1u);
        stp[slot] = ((u32)(d & 255) << 20) | (u32)s;
        stb[slot] = (u16)b;
    }
    __syncthreads();
    for (int b = t; b < NB; b += 512) {
        u32 c = cnt[b];
        gbase[b] = c ? atomicAdd(&bucket_cursor[b], c) : 0;
    }
    __syncthreads();
    for (int s = t; s < nv; s += 512) {
        int b = stb[s];
        ebuf[gbase[b] + (s - lofs[b])] = stp[s];
    }
}

// ---------- pass 2: per-bucket local sort -> csr + rowptr + dinv ----------
__global__ __launch_bounds__(256) void k_scatter2(const u32* __restrict__ bucket_base,
                                                  const u32* __restrict__ ebuf,
                                                  int* __restrict__ rowptr,
                                                  float* __restrict__ dinv,
                                                  int* __restrict__ csr) {
    __shared__ int cnt[256];
    __shared__ int pfx[256];
    __shared__ int lcur[256];
    int b = blockIdx.x, t = threadIdx.x;
    int ebeg = (int)bucket_base[b], eend = (int)bucket_base[b + 1];
    cnt[t] = 0;
    lcur[t] = 0;
    __syncthreads();
    for (int i = ebeg + t; i < eend; i += 256)
        atomicAdd(&cnt[(ebuf[i] >> 20) & 255], 1);
    __syncthreads();
    int v = cnt[t];
    pfx[t] = v;
    __syncthreads();
    for (int off = 1; off < 256; off <<= 1) {
        int a = (t >= off) ? pfx[t - off] : 0;
        __syncthreads();
        pfx[t] += a;
        __syncthreads();
    }
    int node = (b << 8) + t;
    if (node < N_NODES) {
        rowptr[node] = ebeg + (pfx[t] - v);
        dinv[node] = rsqrtf((float)(v + 1));
    }
    __syncthreads();
    for (int i = ebeg + t; i < eend; i += 256) {
        u32 p = ebuf[i];
        int dl = (p >> 20) & 255;
        int pos = ebeg + (pfx[dl] - cnt[dl]) + atomicAdd(&lcur[dl], 1);
        csr[pos] = (int)(p & 0x1FFFFu);
    }
}

// ---------- MFMA GEMM1: g1[N,64] = dinv ⊙ (x[N,256] @ W1[256,64]) ----------
__global__ __launch_bounds__(256) void k_gemm1(const void* __restrict__ xv,
                                               const u16* __restrict__ W1m,
                                               const float* __restrict__ dinv,
                                               u16* __restrict__ g1,
                                               const int* __restrict__ flags) {
    __shared__ u16 wlds[C_IN * C_H];   // 32 KB
    int t = threadIdx.x;
    int isbf = flags[0];
    {
        const uint4* src = (const uint4*)W1m;
        uint4* dst = (uint4*)wlds;
#pragma unroll
        for (int it = 0; it < 8; ++it) dst[t + it * 256] = src[t + it * 256];
    }
    __syncthreads();
    int w = t >> 6, lane = t & 63;
    int quad = lane >> 4, mrow = lane & 15;
    int m0 = blockIdx.x * 128 + w * 32;
    if (m0 >= N_NODES) return;

    bf16x8 a[2][8];
    if (isbf) {
        const u16* xb = (const u16*)xv;
#pragma unroll
        for (int mt = 0; mt < 2; ++mt)
#pragma unroll
            for (int k0 = 0; k0 < 8; ++k0)
                a[mt][k0] = *(const bf16x8*)(xb + (size_t)(m0 + mt * 16 + mrow) * C_IN + k0 * 32 + quad * 8);
    } else {
        const float* xf = (const float*)xv;
#pragma unroll
        for (int mt = 0; mt < 2; ++mt)
#pragma unroll
            for (int k0 = 0; k0 < 8; ++k0) {
                const float* p = xf + (size_t)(m0 + mt * 16 + mrow) * C_IN + k0 * 32 + quad * 8;
                float4 v0 = *(const float4*)p;
                float4 v1 = *(const float4*)(p + 4);
                bf16x8 r;
                r[0] = (short)f2bf(v0.x); r[1] = (short)f2bf(v0.y);
                r[2] = (short)f2bf(v0.z); r[3] = (short)f2bf(v0.w);
                r[4] = (short)f2bf(v1.x); r[5] = (short)f2bf(v1.y);
                r[6] = (short)f2bf(v1.z); r[7] = (short)f2bf(v1.w);
                a[mt][k0] = r;
            }
    }

    float dv0[4], dv1[4];
#pragma unroll
    for (int r = 0; r < 4; ++r) {
        dv0[r] = dinv[m0 + quad * 4 + r];
        dv1[r] = dinv[m0 + 16 + quad * 4 + r];
    }

#pragma unroll
    for (int nt = 0; nt < 4; ++nt) {
        bf16x8 b[8];
#pragma unroll
        for (int k0 = 0; k0 < 8; ++k0)
            b[k0] = *(const bf16x8*)&wlds[((k0 * 4 + nt) * 64 + lane) * 8];
        f32x4 acc0 = {0.f, 0.f, 0.f, 0.f};
        f32x4 acc1 = {0.f, 0.f, 0.f, 0.f};
#pragma unroll
        for (int k0 = 0; k0 < 8; ++k0) {
            acc0 = __builtin_amdgcn_mfma_f32_16x16x32_bf16(a[0][k0], b[k0], acc0, 0, 0, 0);
            acc1 = __builtin_amdgcn_mfma_f32_16x16x32_bf16(a[1][k0], b[k0], acc1, 0, 0, 0);
        }
        int ch = nt * 16 + mrow;   // D: col = lane&15
#pragma unroll
        for (int r = 0; r < 4; ++r) {   // D: row = quad*4 + r
            g1[(size_t)(m0 + quad * 4 + r) * C_H + ch] = f2bf(acc0[r] * dv0[r]);
            g1[(size_t)(m0 + 16 + quad * 4 + r) * C_H + ch] = f2bf(acc1[r] * dv1[r]);
        }
    }
}

// ---------- gather over a pre-scaled 64-channel bf16 table ----------
// One node per 32-lane half; 16 independent 128B rows in flight per wave.
// Table g holds dinv[s]*h[s]; val = dn*(Σ_src g[src] + g[n]).
// MODE 0: a = relu(val + bias); store bf16(dn * a)   (layer-1 -> scaled a1)
// MODE 1: store fp32 val                              (layer-2 agg, pre-GEMM)
template <int MODE>
__global__ __launch_bounds__(256) void k_gatherT(const int* __restrict__ rowptr,
                                                 const int* __restrict__ csr_src,
                                                 const float* __restrict__ dinv,
                                                 const u16* __restrict__ g,
                                                 const float* __restrict__ bias,
                                                 void* __restrict__ outv) {
    int t = threadIdx.x;
    int w = t >> 6, lane = t & 63;
    int half = lane >> 5, j = lane & 31;
    int n = blockIdx.x * 8 + w * 2 + half;
    int beg = rowptr[n], end = rowptr[n + 1];
    float sA = 0.f, sB = 0.f;
    int e = beg;
    for (; e + 7 < end; e += 8) {
        int s[8]; u32 p[8];
#pragma unroll
        for (int q = 0; q < 8; ++q) s[q] = csr_src[e + q];
#pragma unroll
        for (int q = 0; q < 8; ++q) p[q] = *(const u32*)(g + s[q] * C_H + 2 * j);
#pragma unroll
        for (int q = 0; q < 8; ++q) {
            sA += bflo(p[q]);
            sB += bfhi(p[q]);
        }
    }
    for (; e + 3 < end; e += 4) {
        int s[4]; u32 p[4];
#pragma unroll
        for (int q = 0; q < 4; ++q) s[q] = csr_src[e + q];
#pragma unroll
        for (int q = 0; q < 4; ++q) p[q] = *(const u32*)(g + s[q] * C_H + 2 * j);
#pragma unroll
        for (int q = 0; q < 4; ++q) {
            sA += bflo(p[q]);
            sB += bfhi(p[q]);
        }
    }
    for (; e < end; ++e) {
        int s0 = csr_src[e];
        u32 p0 = *(const u32*)(g + s0 * C_H + 2 * j);
        sA += bflo(p0);
        sB += bfhi(p0);
    }
    float dn = dinv[n];
    u32 gn = *(const u32*)(g + n * C_H + 2 * j);
    float vA = dn * (sA + bflo(gn));
    float vB = dn * (sB + bfhi(gn));
    if (MODE == 0) {
        float aA = fmaxf(vA + bias[2 * j], 0.f);
        float aB = fmaxf(vB + bias[2 * j + 1], 0.f);
        u32 pk = (u32)f2bf(dn * aA) | ((u32)f2bf(dn * aB) << 16);
        ((u32*)outv)[n * 32 + j] = pk;
    } else {
        ((float2*)outv)[n * 32 + j] = make_float2(vA, vB);
    }
}

// ---------- fused MFMA GEMM2 + bias + relu + mean-pool partials ----------
__global__ __launch_bounds__(256) void k_fused2(const float* __restrict__ agg,
                                                const u16* __restrict__ W2m,
                                                const float* __restrict__ b2c,
                                                float* __restrict__ partial) {
    __shared__ float psum[4 * 8 * 64];   // [wave][nt][lane], 8 KB
    int t = threadIdx.x;
    int w = t >> 6, lane = t & 63;
    int quad = lane >> 4, m = lane & 15;

    bf16x8 b[2][8];
#pragma unroll
    for (int k0 = 0; k0 < 2; ++k0)
#pragma unroll
        for (int nt = 0; nt < 8; ++nt)
            b[k0][nt] = *(const bf16x8*)&W2m[((k0 * 8 + nt) * 64 + lane) * 8];

    float pacc[8] = {0.f, 0.f, 0.f, 0.f, 0.f, 0.f, 0.f, 0.f};
    float bias[8];
#pragma unroll
    for (int nt = 0; nt < 8; ++nt) bias[nt] = b2c[nt * 16 + m];

    for (int tile = blockIdx.x * 4 + w; tile < NTILES; tile += G2F * 4) {
        const float* arow = agg + (size_t)(tile * 16 + m) * C_H + quad * 8;
        bf16x8 a[2];
#pragma unroll
        for (int k0 = 0; k0 < 2; ++k0) {
            float4 v0 = *(const float4*)(arow + k0 * 32);
            float4 v1 = *(const float4*)(arow + k0 * 32 + 4);
            bf16x8 r;
            r[0] = (short)f2bf(v0.x); r[1] = (short)f2bf(v0.y);
            r[2] = (short)f2bf(v0.z); r[3] = (short)f2bf(v0.w);
            r[4] = (short)f2bf(v1.x); r[5] = (short)f2bf(v1.y);
            r[6] = (short)f2bf(v1.z); r[7] = (short)f2bf(v1.w);
            a[k0] = r;
        }
#pragma unroll
        for (int nt = 0; nt < 8; ++nt) {
            f32x4 acc = {0.f, 0.f, 0.f, 0.f};
            acc = __builtin_amdgcn_mfma_f32_16x16x32_bf16(a[0], b[0][nt], acc, 0, 0, 0);
            acc = __builtin_amdgcn_mfma_f32_16x16x32_bf16(a[1], b[1][nt], acc, 0, 0, 0);
#pragma unroll
            for (int r = 0; r < 4; ++r)
                pacc[nt] += fmaxf(acc[r] + bias[nt], 0.f);
        }
    }
#pragma unroll
    for (int nt = 0; nt < 8; ++nt) psum[(w * 8 + nt) * 64 + lane] = pacc[nt];
    __syncthreads();
    if (t < 128) {
        int nt = t >> 4, m2 = t & 15;
        float s = 0.f;
#pragma unroll
        for (int ww = 0; ww < 4; ++ww)
#pragma unroll
            for (int q = 0; q < 4; ++q)
                s += psum[(ww * 8 + nt) * 64 + q * 16 + m2];
        partial[blockIdx.x * C_OUT + t] = s;   // ch = nt*16 + m2 = t
    }
}

// ---------- final: mean + FC -> 2 outputs (dtype per flag) ----------
__global__ __launch_bounds__(512) void k_final(const float* __restrict__ partial,
                                               const float* __restrict__ fcWc,
                                               const float* __restrict__ fcbc,
                                               void* __restrict__ out,
                                               const int* __restrict__ flags) {
    __shared__ float sm[512];
    __shared__ float red[256];
    int t = threadIdx.x;
    int f = t & 127, c = t >> 7;
    float s = 0.f;
    for (int b = c; b < G2F; b += 4) s += partial[b * 128 + f];
    sm[t] = s;
    __syncthreads();
    if (t < 128) {
        float gm = (sm[t] + sm[t + 128] + sm[t + 256] + sm[t + 384]) * (1.0f / (float)N_NODES);
        red[t] = gm * fcWc[t];
        red[128 + t] = gm * fcWc[128 + t];
    }
    __syncthreads();
    for (int off = 64; off >= 1; off >>= 1) {
        if (t < off) {
            red[t] += red[t + off];
            red[128 + t] += red[128 + t + off];
        }
        __syncthreads();
    }
    if (t == 0) {
        float o0 = red[0] + fcbc[0];
        float o1 = red[128] + fcbc[1];
        if (flags[0]) {
            u16* ob = (u16*)out;
            ob[0] = f2bf(o0);
            ob[1] = f2bf(o1);
        } else {
            float* of = (float*)out;
            of[0] = o0;
            of[1] = o1;
        }
    }
}

// ---------- workspace layout (bytes) ----------
// ebuf aliases AGG: ebuf's last read (k_scatter2) precedes agg's first write
// (k_gatherT<1>) in stream order.
#define OFF_FLAGS   0u
#define OFF_DINV    512u        // float[N]
#define OFF_ROWPTR  400896u     // int[N+1]
#define OFF_BCNT    801280u     // u32[NB]
#define OFF_BBASE   802944u     // u32[NB+1]
#define OFF_BCUR    804608u     // u32[NB]
#define OFF_CSR     1201664u    // int[E]
#define OFF_H1      14001664u   // bf16[N*64]  (g1 = dinv*h1)
#define OFF_A1      26801664u   // bf16[N*64]  (a1s = dinv*a1)
#define OFF_AGG     39601664u   // float[N*64] (25.6MB) / ebuf u32[E] (12.8MB)
#define OFF_PART    65201664u   // float[G2F*128]
#define OFF_W1C     65728000u   // u16[256*64] (MFMA frag order)
#define OFF_W2C     65760768u   // u16[64*128] (MFMA frag order)
#define OFF_B1C     65777152u   // float[64]
#define OFF_B2C     65777408u   // float[128]
#define OFF_FCWC    65777920u   // float[256]
#define OFF_FCBC    65778944u   // float[2]

extern "C" void kernel_launch(void* const* d_in, const int* in_sizes, int n_in,
                              void* d_out, int out_size, void* d_ws, size_t ws_size,
                              hipStream_t stream) {
    (void)in_sizes; (void)n_in; (void)out_size; (void)ws_size;
    const void* x   = d_in[0];
    const int*  ei  = (const int*)d_in[1];
    const void* W1  = d_in[2];
    const void* b1  = d_in[3];
    const void* W2  = d_in[4];
    const void* b2  = d_in[5];
    const void* fcW = d_in[6];
    const void* fcb = d_in[7];

    char* ws = (char*)d_ws;
    int*   flags  = (int*)(ws + OFF_FLAGS);
    float* dinv   = (float*)(ws + OFF_DINV);
    int*   rowptr = (int*)(ws + OFF_ROWPTR);
    u32*   bcnt   = (u32*)(ws + OFF_BCNT);
    u32*   bbase  = (u32*)(ws + OFF_BBASE);
    u32*   bcur   = (u32*)(ws + OFF_BCUR);
    int*   csr    = (int*)(ws + OFF_CSR);
    u16*   g1     = (u16*)(ws + OFF_H1);
    u16*   a1s    = (u16*)(ws + OFF_A1);
    float* agg    = (float*)(ws + OFF_AGG);
    u32*   ebuf   = (u32*)(ws + OFF_AGG);
    float* partial= (float*)(ws + OFF_PART);
    u16*   W1m    = (u16*)(ws + OFF_W1C);
    u16*   W2m    = (u16*)(ws + OFF_W2C);
    float* b1c    = (float*)(ws + OFF_B1C);
    float* b2c    = (float*)(ws + OFF_B2C);
    float* fcWc   = (float*)(ws + OFF_FCWC);
    float* fcbc   = (float*)(ws + OFF_FCBC);

    k_detect<<<1, 256, 0, stream>>>(x, ei, b1, b2, fcW, fcb,
                                    flags, b1c, b2c, fcWc, fcbc);
    k_prep<<<96, 256, 0, stream>>>(W1, W2, flags, W1m, W2m, bcnt);
    k_hist1<<<NB, 256, 0, stream>>>(ei, flags, bcnt);
    k_bscan<<<1, 512, 0, stream>>>(bcnt, bbase, bcur, rowptr);
    k_scatter1<<<NB, 512, 0, stream>>>(ei, flags, bcur, ebuf);
    k_scatter2<<<NB, 256, 0, stream>>>(bbase, ebuf, rowptr, dinv, csr);
    k_gemm1<<<(N_NODES + 127) / 128, 256, 0, stream>>>(x, W1m, dinv, g1, flags);
    k_gatherT<0><<<N_NODES / 8, 256, 0, stream>>>(rowptr, csr, dinv, g1, b1c, (void*)a1s);
    k_gatherT<1><<<N_NODES / 8, 256, 0, stream>>>(rowptr, csr, dinv, a1s, (const float*)nullptr, (void*)agg);
    k_fused2<<<G2F, 256, 0, stream>>>(agg, W2m, b2c, partial);
    k_final<<<1, 512, 0, stream>>>(partial, fcWc, fcbc, (void*)d_out, flags);
}

// Round 8
// 415.790 us; speedup vs baseline: 3.2689x; 1.0077x over previous
//
#include <hip/hip_runtime.h>

#define N_NODES 100000
#define N_EDGES 3200000
#define C_IN 256
#define C_H 64
#define C_OUT 128
#define NB 391       // ceil(N_NODES/256) buckets of 256 nodes
#define G2F 625      // blocks for fused gemm2+pool
#define NTILES 6250  // N_NODES/16
#define CH1 8192     // edges per block in hist/scatter1

typedef unsigned int u32;
typedef unsigned short u16;
typedef unsigned long long u64;
typedef __attribute__((ext_vector_type(8))) short bf16x8;
typedef __attribute__((ext_vector_type(4))) float f32x4;

// ---------- bf16 helpers ----------
__device__ __forceinline__ float bflo(u32 p) {
    union { u32 i; float f; } v; v.i = p << 16; return v.f;
}
__device__ __forceinline__ float bfhi(u32 p) {
    union { u32 i; float f; } v; v.i = p & 0xffff0000u; return v.f;
}
__device__ __forceinline__ float bf2f(u16 u) {
    union { u32 i; float f; } v; v.i = ((u32)u) << 16; return v.f;
}
__device__ __forceinline__ u16 f2bf(float f) {
    union { float f; u32 i; } v; v.f = f;
    u32 x = v.i;
    return (u16)((x + 0x7fffu + ((x >> 16) & 1u)) >> 16);  // RNE
}

// ---------- slim detection: flags + small tensors ----------
__global__ void k_detect(const void* __restrict__ x, const void* __restrict__ ei,
                         const void* __restrict__ b1, const void* __restrict__ b2,
                         const void* __restrict__ fcW, const void* __restrict__ fcb,
                         int* __restrict__ flags,
                         float* __restrict__ b1c, float* __restrict__ b2c,
                         float* __restrict__ fcWc, float* __restrict__ fcbc) {
    __shared__ int sf[2];
    int t = threadIdx.x;
    if (t < 64) {
        u32 w = ((const u32*)x)[t];
        u32 low = w & 0xffffu;
        int e = (int)((low >> 7) & 0xff);
        bool inw = (e > 96 && e < 160) || (low == 0);
        u64 m = __ballot(inw);
        if (t == 0) sf[0] = (__popcll(m) >= 60) ? 1 : 0;
    } else if (t < 128) {
        int i = t - 64;
        u32 w = ((const u32*)ei)[2 * i + 1];
        u64 m = __ballot(w == 0);
        if (i == 0) sf[1] = (m == ~0ull) ? 1 : 0;
    }
    __syncthreads();
    if (t == 0) { flags[0] = sf[0]; flags[1] = sf[1]; }
    int isbf = sf[0];
    if (isbf) {
        const u16* p1 = (const u16*)b1;  const u16* p2 = (const u16*)b2;
        const u16* pw = (const u16*)fcW; const u16* pb = (const u16*)fcb;
        for (int i = t; i < C_H; i += 256) b1c[i] = bf2f(p1[i]);
        for (int i = t; i < C_OUT; i += 256) b2c[i] = bf2f(p2[i]);
        for (int i = t; i < 2 * C_OUT; i += 256) fcWc[i] = bf2f(pw[i]);
        for (int i = t; i < 2; i += 256) fcbc[i] = bf2f(pb[i]);
    } else {
        const float* p1 = (const float*)b1;  const float* p2 = (const float*)b2;
        const float* pw = (const float*)fcW; const float* pb = (const float*)fcb;
        for (int i = t; i < C_H; i += 256) b1c[i] = p1[i];
        for (int i = t; i < C_OUT; i += 256) b2c[i] = p2[i];
        for (int i = t; i < 2 * C_OUT; i += 256) fcWc[i] = pw[i];
        for (int i = t; i < 2; i += 256) fcbc[i] = pb[i];
    }
}

// ---------- parallel prep: W1m/W2m frag-order swizzles + bucket_cnt zero ----------
__global__ __launch_bounds__(256) void k_prep(const void* __restrict__ W1,
                                              const void* __restrict__ W2,
                                              const int* __restrict__ flags,
                                              u16* __restrict__ W1m, u16* __restrict__ W2m,
                                              u32* __restrict__ bucket_cnt) {
    int b = blockIdx.x, t = threadIdx.x;
    int isbf = flags[0];
    int i = b * 256 + t;
    if (i < NB) bucket_cnt[i] = 0;
    if (i < C_IN * C_H) {
        const u16* w1b = (const u16*)W1; const float* w1f = (const float*)W1;
        int j = i & 7, lane = (i >> 3) & 63, nt = (i >> 9) & 3, k0 = i >> 11;
        int k = k0 * 32 + ((lane >> 4) & 3) * 8 + j;
        int n = nt * 16 + (lane & 15);
        W1m[i] = isbf ? w1b[k * C_H + n] : f2bf(w1f[k * C_H + n]);
    } else {
        int i2 = i - C_IN * C_H;
        const u16* w2b = (const u16*)W2; const float* w2f = (const float*)W2;
        int j = i2 & 7, lane = (i2 >> 3) & 63, nt = (i2 >> 9) & 7, k0 = (i2 >> 12) & 1;
        int k = k0 * 32 + ((lane >> 4) & 3) * 8 + j;
        int n = nt * 16 + (lane & 15);
        W2m[i2] = isbf ? w2b[k * C_OUT + n] : f2bf(w2f[k * C_OUT + n]);
    }
}

// ---------- bucket histogram over dst>>8 ----------
__global__ __launch_bounds__(256) void k_hist1(const int* __restrict__ ei,
                                               const int* __restrict__ flags,
                                               u32* __restrict__ bucket_cnt) {
    __shared__ u32 h[NB];
    int t = threadIdx.x;
    int is64 = flags[1];
    for (int i = t; i < NB; i += 256) h[i] = 0;
    __syncthreads();
    int e0 = blockIdx.x * CH1;
    int nv = min(CH1, N_EDGES - e0);
    for (int i = t; i < nv; i += 256) {
        int e = e0 + i;
        int d = is64 ? ei[2 * (N_EDGES + e)] : ei[N_EDGES + e];
        atomicAdd(&h[d >> 8], 1u);
    }
    __syncthreads();
    for (int i = t; i < NB; i += 256)
        if (h[i]) atomicAdd(&bucket_cnt[i], h[i]);
}

// ---------- scan bucket counts -> base + cursor ----------
__global__ __launch_bounds__(512) void k_bscan(const u32* __restrict__ bucket_cnt,
                                               u32* __restrict__ bucket_base,
                                               u32* __restrict__ bucket_cursor,
                                               int* __restrict__ rowptr) {
    __shared__ u32 sm[512];
    int t = threadIdx.x;
    u32 v = (t < NB) ? bucket_cnt[t] : 0;
    sm[t] = v;
    __syncthreads();
    for (int off = 1; off < 512; off <<= 1) {
        u32 a = (t >= off) ? sm[t - off] : 0;
        __syncthreads();
        sm[t] += a;
        __syncthreads();
    }
    if (t < NB) {
        u32 excl = sm[t] - v;
        bucket_base[t] = excl;
        bucket_cursor[t] = excl;
    }
    if (t == 0) {
        bucket_base[NB] = N_EDGES;
        rowptr[N_NODES] = N_EDGES;
    }
}

// ---------- pass 1: bucket-sorted staged scatter (line-dense writes) ----------
__global__ __launch_bounds__(512) void k_scatter1(const int* __restrict__ ei,
                                                  const int* __restrict__ flags,
                                                  u32* __restrict__ bucket_cursor,
                                                  u32* __restrict__ ebuf) {
    __shared__ u32 cnt[NB];
    __shared__ u32 lcur[NB];
    __shared__ u32 gbase[NB];
    __shared__ u32 lofs[512];
    __shared__ u32 stp[CH1];
    __shared__ u16 stb[CH1];
    int t = threadIdx.x;
    int is64 = flags[1];
    int e0 = blockIdx.x * CH1;
    int nv = min(CH1, N_EDGES - e0);
    for (int i = t; i < NB; i += 512) { cnt[i] = 0; lcur[i] = 0; }
    __syncthreads();
    for (int i = t; i < nv; i += 512) {
        int e = e0 + i;
        int d = is64 ? ei[2 * (N_EDGES + e)] : ei[N_EDGES + e];
        atomicAdd(&cnt[d >> 8], 1u);
    }
    __syncthreads();
    u32 v = (t < NB) ? cnt[t] : 0;
    lofs[t] = v;
    __syncthreads();
    for (int off = 1; off < 512; off <<= 1) {
        u32 a = (t >= off) ? lofs[t - off] : 0;
        __syncthreads();
        lofs[t] += a;
        __syncthreads();
    }
    u32 excl = lofs[t] - v;
    __syncthreads();
    lofs[t] = excl;
    __syncthreads();
    for (int i = t; i < nv; i += 512) {
        int e = e0 + i;
        int d, s;
        if (is64) { d = ei[2 * (N_EDGES + e)]; s = ei[2 * e]; }
        else      { d = ei[N_EDGES + e];       s = ei[e]; }
        int b = d >> 8;
        u32 slot = lofs[b] + atomicAdd(&lcur[b], 1u);
        stp[slot] = ((u32)(d & 255) << 20) | (u32)s;
        stb[slot] = (u16)b;
    }
    __syncthreads();
    for (int b = t; b < NB; b += 512) {
        u32 c = cnt[b];
        gbase[b] = c ? atomicAdd(&bucket_cursor[b], c) : 0;
    }
    __syncthreads();
    for (int s = t; s < nv; s += 512) {
        int b = stb[s];
        ebuf[gbase[b] + (s - lofs[b])] = stp[s];
    }
}

// ---------- pass 2: per-bucket local sort -> csr + rowptr + dinv ----------
__global__ __launch_bounds__(256) void k_scatter2(const u32* __restrict__ bucket_base,
                                                  const u32* __restrict__ ebuf,
                                                  int* __restrict__ rowptr,
                                                  float* __restrict__ dinv,
                                                  int* __restrict__ csr) {
    __shared__ int cnt[256];
    __shared__ int pfx[256];
    __shared__ int lcur[256];
    int b = blockIdx.x, t = threadIdx.x;
    int ebeg = (int)bucket_base[b], eend = (int)bucket_base[b + 1];
    cnt[t] = 0;
    lcur[t] = 0;
    __syncthreads();
    for (int i = ebeg + t; i < eend; i += 256)
        atomicAdd(&cnt[(ebuf[i] >> 20) & 255], 1);
    __syncthreads();
    int v = cnt[t];
    pfx[t] = v;
    __syncthreads();
    for (int off = 1; off < 256; off <<= 1) {
        int a = (t >= off) ? pfx[t - off] : 0;
        __syncthreads();
        pfx[t] += a;
        __syncthreads();
    }
    int node = (b << 8) + t;
    if (node < N_NODES) {
        rowptr[node] = ebeg + (pfx[t] - v);
        dinv[node] = rsqrtf((float)(v + 1));
    }
    __syncthreads();
    for (int i = ebeg + t; i < eend; i += 256) {
        u32 p = ebuf[i];
        int dl = (p >> 20) & 255;
        int pos = ebeg + (pfx[dl] - cnt[dl]) + atomicAdd(&lcur[dl], 1);
        csr[pos] = (int)(p & 0x1FFFFu);
    }
}

// ---------- MFMA GEMM1: g1[N,64] = dinv ⊙ (x[N,256] @ W1[256,64]) ----------
__global__ __launch_bounds__(256) void k_gemm1(const void* __restrict__ xv,
                                               const u16* __restrict__ W1m,
                                               const float* __restrict__ dinv,
                                               u16* __restrict__ g1,
                                               const int* __restrict__ flags) {
    __shared__ u16 wlds[C_IN * C_H];   // 32 KB
    int t = threadIdx.x;
    int isbf = flags[0];
    {
        const uint4* src = (const uint4*)W1m;
        uint4* dst = (uint4*)wlds;
#pragma unroll
        for (int it = 0; it < 8; ++it) dst[t + it * 256] = src[t + it * 256];
    }
    __syncthreads();
    int w = t >> 6, lane = t & 63;
    int quad = lane >> 4, mrow = lane & 15;
    int m0 = blockIdx.x * 128 + w * 32;
    if (m0 >= N_NODES) return;

    bf16x8 a[2][8];
    if (isbf) {
        const u16* xb = (const u16*)xv;
#pragma unroll
        for (int mt = 0; mt < 2; ++mt)
#pragma unroll
            for (int k0 = 0; k0 < 8; ++k0)
                a[mt][k0] = *(const bf16x8*)(xb + (size_t)(m0 + mt * 16 + mrow) * C_IN + k0 * 32 + quad * 8);
    } else {
        const float* xf = (const float*)xv;
#pragma unroll
        for (int mt = 0; mt < 2; ++mt)
#pragma unroll
            for (int k0 = 0; k0 < 8; ++k0) {
                const float* p = xf + (size_t)(m0 + mt * 16 + mrow) * C_IN + k0 * 32 + quad * 8;
                float4 v0 = *(const float4*)p;
                float4 v1 = *(const float4*)(p + 4);
                bf16x8 r;
                r[0] = (short)f2bf(v0.x); r[1] = (short)f2bf(v0.y);
                r[2] = (short)f2bf(v0.z); r[3] = (short)f2bf(v0.w);
                r[4] = (short)f2bf(v1.x); r[5] = (short)f2bf(v1.y);
                r[6] = (short)f2bf(v1.z); r[7] = (short)f2bf(v1.w);
                a[mt][k0] = r;
            }
    }

    float dv0[4], dv1[4];
#pragma unroll
    for (int r = 0; r < 4; ++r) {
        dv0[r] = dinv[m0 + quad * 4 + r];
        dv1[r] = dinv[m0 + 16 + quad * 4 + r];
    }

#pragma unroll
    for (int nt = 0; nt < 4; ++nt) {
        bf16x8 b[8];
#pragma unroll
        for (int k0 = 0; k0 < 8; ++k0)
            b[k0] = *(const bf16x8*)&wlds[((k0 * 4 + nt) * 64 + lane) * 8];
        f32x4 acc0 = {0.f, 0.f, 0.f, 0.f};
        f32x4 acc1 = {0.f, 0.f, 0.f, 0.f};
#pragma unroll
        for (int k0 = 0; k0 < 8; ++k0) {
            acc0 = __builtin_amdgcn_mfma_f32_16x16x32_bf16(a[0][k0], b[k0], acc0, 0, 0, 0);
            acc1 = __builtin_amdgcn_mfma_f32_16x16x32_bf16(a[1][k0], b[k0], acc1, 0, 0, 0);
        }
        int ch = nt * 16 + mrow;   // D: col = lane&15
#pragma unroll
        for (int r = 0; r < 4; ++r) {   // D: row = quad*4 + r
            g1[(size_t)(m0 + quad * 4 + r) * C_H + ch] = f2bf(acc0[r] * dv0[r]);
            g1[(size_t)(m0 + 16 + quad * 4 + r) * C_H + ch] = f2bf(acc1[r] * dv1[r]);
        }
    }
}

// ---------- gather: one node per wave, lane = (edge-group, channel-octet) ----------
// Lane = grp*8 + c: grp = edge slot (stride 8), c = channel octet (8 bf16, 16B).
// One dwordx4 instruction covers 8 edge-rows. Butterfly over grp at the end.
// Table g holds dinv[s]*h[s]; val = dn*(Σ_src g[src] + g[n]).
// MODE 0: store bf16(dn * relu(val + bias))   MODE 1: store bf16(val)
template <int MODE>
__global__ __launch_bounds__(256) void k_gatherT(const int* __restrict__ rowptr,
                                                 const int* __restrict__ csr_src,
                                                 const float* __restrict__ dinv,
                                                 const u16* __restrict__ g,
                                                 const float* __restrict__ bias,
                                                 u16* __restrict__ out) {
    int t = threadIdx.x;
    int w = t >> 6, lane = t & 63;
    int grp = lane >> 3, c = lane & 7;
    int n = blockIdx.x * 4 + w;
    int beg = rowptr[n], end = rowptr[n + 1];
    float acc[8] = {0.f, 0.f, 0.f, 0.f, 0.f, 0.f, 0.f, 0.f};
    int e = beg + grp;
    for (; e + 8 < end; e += 16) {
        int sa = csr_src[e];
        int sb = csr_src[e + 8];
        uint4 pa = *(const uint4*)(g + (size_t)sa * C_H + c * 8);
        uint4 pb = *(const uint4*)(g + (size_t)sb * C_H + c * 8);
        acc[0] += bflo(pa.x); acc[1] += bfhi(pa.x);
        acc[2] += bflo(pa.y); acc[3] += bfhi(pa.y);
        acc[4] += bflo(pa.z); acc[5] += bfhi(pa.z);
        acc[6] += bflo(pa.w); acc[7] += bfhi(pa.w);
        acc[0] += bflo(pb.x); acc[1] += bfhi(pb.x);
        acc[2] += bflo(pb.y); acc[3] += bfhi(pb.y);
        acc[4] += bflo(pb.z); acc[5] += bfhi(pb.z);
        acc[6] += bflo(pb.w); acc[7] += bfhi(pb.w);
    }
    if (e < end) {
        int sa = csr_src[e];
        uint4 pa = *(const uint4*)(g + (size_t)sa * C_H + c * 8);
        acc[0] += bflo(pa.x); acc[1] += bfhi(pa.x);
        acc[2] += bflo(pa.y); acc[3] += bfhi(pa.y);
        acc[4] += bflo(pa.z); acc[5] += bfhi(pa.z);
        acc[6] += bflo(pa.w); acc[7] += bfhi(pa.w);
    }
    // combine the 8 edge-groups (lanes differing in bits 3..5)
#pragma unroll
    for (int i = 0; i < 8; ++i) {
        acc[i] += __shfl_xor(acc[i], 8, 64);
        acc[i] += __shfl_xor(acc[i], 16, 64);
        acc[i] += __shfl_xor(acc[i], 32, 64);
    }
    if (grp == 0) {   // lanes 0..7 finalize; lane c owns channels c*8..c*8+7
        float dn = dinv[n];
        uint4 pn = *(const uint4*)(g + (size_t)n * C_H + c * 8);
        float sf[8];
        sf[0] = bflo(pn.x); sf[1] = bfhi(pn.x);
        sf[2] = bflo(pn.y); sf[3] = bfhi(pn.y);
        sf[4] = bflo(pn.z); sf[5] = bfhi(pn.z);
        sf[6] = bflo(pn.w); sf[7] = bfhi(pn.w);
        u32 res[4];
#pragma unroll
        for (int k = 0; k < 4; ++k) {
            float vA = dn * (acc[2 * k] + sf[2 * k]);
            float vB = dn * (acc[2 * k + 1] + sf[2 * k + 1]);
            if (MODE == 0) {
                vA = dn * fmaxf(vA + bias[c * 8 + 2 * k], 0.f);
                vB = dn * fmaxf(vB + bias[c * 8 + 2 * k + 1], 0.f);
            }
            res[k] = (u32)f2bf(vA) | ((u32)f2bf(vB) << 16);
        }
        uint4 pk;
        pk.x = res[0]; pk.y = res[1]; pk.z = res[2]; pk.w = res[3];
        *(uint4*)(out + (size_t)n * C_H + c * 8) = pk;
    }
}

// ---------- fused MFMA GEMM2 + bias + relu + mean-pool partials ----------
// A = agg bf16 table (pre-rounded), B = W2m frag-order.
__global__ __launch_bounds__(256) void k_fused2(const u16* __restrict__ aggb,
                                                const u16* __restrict__ W2m,
                                                const float* __restrict__ b2c,
                                                float* __restrict__ partial) {
    __shared__ float psum[4 * 8 * 64];   // [wave][nt][lane], 8 KB
    int t = threadIdx.x;
    int w = t >> 6, lane = t & 63;
    int quad = lane >> 4, m = lane & 15;

    bf16x8 b[2][8];
#pragma unroll
    for (int k0 = 0; k0 < 2; ++k0)
#pragma unroll
        for (int nt = 0; nt < 8; ++nt)
            b[k0][nt] = *(const bf16x8*)&W2m[((k0 * 8 + nt) * 64 + lane) * 8];

    float pacc[8] = {0.f, 0.f, 0.f, 0.f, 0.f, 0.f, 0.f, 0.f};
    float bias[8];
#pragma unroll
    for (int nt = 0; nt < 8; ++nt) bias[nt] = b2c[nt * 16 + m];

    for (int tile = blockIdx.x * 4 + w; tile < NTILES; tile += G2F * 4) {
        const u16* arow = aggb + (size_t)(tile * 16 + m) * C_H + quad * 8;
        bf16x8 a0 = *(const bf16x8*)(arow);
        bf16x8 a1 = *(const bf16x8*)(arow + 32);
#pragma unroll
        for (int nt = 0; nt < 8; ++nt) {
            f32x4 acc = {0.f, 0.f, 0.f, 0.f};
            acc = __builtin_amdgcn_mfma_f32_16x16x32_bf16(a0, b[0][nt], acc, 0, 0, 0);
            acc = __builtin_amdgcn_mfma_f32_16x16x32_bf16(a1, b[1][nt], acc, 0, 0, 0);
#pragma unroll
            for (int r = 0; r < 4; ++r)
                pacc[nt] += fmaxf(acc[r] + bias[nt], 0.f);
        }
    }
#pragma unroll
    for (int nt = 0; nt < 8; ++nt) psum[(w * 8 + nt) * 64 + lane] = pacc[nt];
    __syncthreads();
    if (t < 128) {
        int nt = t >> 4, m2 = t & 15;
        float s = 0.f;
#pragma unroll
        for (int ww = 0; ww < 4; ++ww)
#pragma unroll
            for (int q = 0; q < 4; ++q)
                s += psum[(ww * 8 + nt) * 64 + q * 16 + m2];
        partial[blockIdx.x * C_OUT + t] = s;   // ch = nt*16 + m2 = t
    }
}

// ---------- final: mean + FC -> 2 outputs (dtype per flag) ----------
__global__ __launch_bounds__(512) void k_final(const float* __restrict__ partial,
                                               const float* __restrict__ fcWc,
                                               const float* __restrict__ fcbc,
                                               void* __restrict__ out,
                                               const int* __restrict__ flags) {
    __shared__ float sm[512];
    __shared__ float red[256];
    int t = threadIdx.x;
    int f = t & 127, c = t >> 7;
    float s = 0.f;
    for (int b = c; b < G2F; b += 4) s += partial[b * 128 + f];
    sm[t] = s;
    __syncthreads();
    if (t < 128) {
        float gm = (sm[t] + sm[t + 128] + sm[t + 256] + sm[t + 384]) * (1.0f / (float)N_NODES);
        red[t] = gm * fcWc[t];
        red[128 + t] = gm * fcWc[128 + t];
    }
    __syncthreads();
    for (int off = 64; off >= 1; off >>= 1) {
        if (t < off) {
            red[t] += red[t + off];
            red[128 + t] += red[128 + t + off];
        }
        __syncthreads();
    }
    if (t == 0) {
        float o0 = red[0] + fcbc[0];
        float o1 = red[128] + fcbc[1];
        if (flags[0]) {
            u16* ob = (u16*)out;
            ob[0] = f2bf(o0);
            ob[1] = f2bf(o1);
        } else {
            float* of = (float*)out;
            of[0] = o0;
            of[1] = o1;
        }
    }
}

// ---------- workspace layout (bytes) ----------
// agg (bf16, 12.8MB) aliases ebuf u32[E] (12.8MB): ebuf's last read (k_scatter2)
// precedes agg's first write (k_gatherT<1>) in stream order.
#define OFF_FLAGS   0u
#define OFF_DINV    512u        // float[N]
#define OFF_ROWPTR  400896u     // int[N+1]
#define OFF_BCNT    801280u     // u32[NB]
#define OFF_BBASE   802944u     // u32[NB+1]
#define OFF_BCUR    804608u     // u32[NB]
#define OFF_CSR     1201664u    // int[E]
#define OFF_H1      14001664u   // bf16[N*64]  (g1 = dinv*h1)
#define OFF_A1      26801664u   // bf16[N*64]  (a1s = dinv*a1)
#define OFF_AGG     39601664u   // bf16[N*64] (12.8MB) / ebuf u32[E] (12.8MB)
#define OFF_PART    65201664u   // float[G2F*128]
#define OFF_W1C     65728000u   // u16[256*64] (MFMA frag order)
#define OFF_W2C     65760768u   // u16[64*128] (MFMA frag order)
#define OFF_B1C     65777152u   // float[64]
#define OFF_B2C     65777408u   // float[128]
#define OFF_FCWC    65777920u   // float[256]
#define OFF_FCBC    65778944u   // float[2]

extern "C" void kernel_launch(void* const* d_in, const int* in_sizes, int n_in,
                              void* d_out, int out_size, void* d_ws, size_t ws_size,
                              hipStream_t stream) {
    (void)in_sizes; (void)n_in; (void)out_size; (void)ws_size;
    const void* x   = d_in[0];
    const int*  ei  = (const int*)d_in[1];
    const void* W1  = d_in[2];
    const void* b1  = d_in[3];
    const void* W2  = d_in[4];
    const void* b2  = d_in[5];
    const void* fcW = d_in[6];
    const void* fcb = d_in[7];

    char* ws = (char*)d_ws;
    int*   flags  = (int*)(ws + OFF_FLAGS);
    float* dinv   = (float*)(ws + OFF_DINV);
    int*   rowptr = (int*)(ws + OFF_ROWPTR);
    u32*   bcnt   = (u32*)(ws + OFF_BCNT);
    u32*   bbase  = (u32*)(ws + OFF_BBASE);
    u32*   bcur   = (u32*)(ws + OFF_BCUR);
    int*   csr    = (int*)(ws + OFF_CSR);
    u16*   g1     = (u16*)(ws + OFF_H1);
    u16*   a1s    = (u16*)(ws + OFF_A1);
    u16*   aggb   = (u16*)(ws + OFF_AGG);
    u32*   ebuf   = (u32*)(ws + OFF_AGG);
    float* partial= (float*)(ws + OFF_PART);
    u16*   W1m    = (u16*)(ws + OFF_W1C);
    u16*   W2m    = (u16*)(ws + OFF_W2C);
    float* b1c    = (float*)(ws + OFF_B1C);
    float* b2c    = (float*)(ws + OFF_B2C);
    float* fcWc   = (float*)(ws + OFF_FCWC);
    float* fcbc   = (float*)(ws + OFF_FCBC);

    k_detect<<<1, 256, 0, stream>>>(x, ei, b1, b2, fcW, fcb,
                                    flags, b1c, b2c, fcWc, fcbc);
    k_prep<<<96, 256, 0, stream>>>(W1, W2, flags, W1m, W2m, bcnt);
    k_hist1<<<NB, 256, 0, stream>>>(ei, flags, bcnt);
    k_bscan<<<1, 512, 0, stream>>>(bcnt, bbase, bcur, rowptr);
    k_scatter1<<<NB, 512, 0, stream>>>(ei, flags, bcur, ebuf);
    k_scatter2<<<NB, 256, 0, stream>>>(bbase, ebuf, rowptr, dinv, csr);
    k_gemm1<<<(N_NODES + 127) / 128, 256, 0, stream>>>(x, W1m, dinv, g1, flags);
    k_gatherT<0><<<N_NODES / 4, 256, 0, stream>>>(rowptr, csr, dinv, g1, b1c, a1s);
    k_gatherT<1><<<N_NODES / 4, 256, 0, stream>>>(rowptr, csr, dinv, a1s, (const float*)nullptr, aggb);
    k_fused2<<<G2F, 256, 0, stream>>>(aggb, W2m, b2c, partial);
    k_final<<<1, 512, 0, stream>>>(partial, fcWc, fcbc, (void*)d_out, flags);
}